// Round 1
// baseline (1078.308 us; speedup 1.0000x reference)
//
#include <hip/hip_runtime.h>

#define EPS 1e-3f

// ---------------------------------------------------------------------------
// Kernel 1: conv1 (3x3, 3->32, SAME) + bias + relu + BN + 2x2 maxpool
// x: [2048,32,32,3]  -> h1: [2048,16,16,32]
// BN applied after pool: exact because bn1g > 0 (monotone).
// ---------------------------------------------------------------------------
__global__ __launch_bounds__(256) void k_conv1(
    const float* __restrict__ x, const float* __restrict__ W,
    const float* __restrict__ bias,
    const float* __restrict__ g, const float* __restrict__ bb,
    const float* __restrict__ m, const float* __restrict__ v,
    float* __restrict__ out)
{
    int t = blockIdx.x * blockDim.x + threadIdx.x;   // 2048*16*16*32
    int co = t & 31;
    int px = (t >> 5) & 15;
    int py = (t >> 9) & 15;
    int b  = t >> 13;

    int y0 = 2 * py - 1, x0 = 2 * px - 1;
    float patch[4][4][3];
#pragma unroll
    for (int r = 0; r < 4; ++r) {
        int y = y0 + r;
        bool yok = ((unsigned)y < 32u);
#pragma unroll
        for (int c = 0; c < 4; ++c) {
            int xx = x0 + c;
            bool ok = yok && ((unsigned)xx < 32u);
            const float* p = x + (((long)b * 32 + y) * 32 + xx) * 3;
#pragma unroll
            for (int ci = 0; ci < 3; ++ci)
                patch[r][c][ci] = ok ? p[ci] : 0.f;
        }
    }

    float bv = bias[co];
    float a00 = bv, a01 = bv, a10 = bv, a11 = bv;
#pragma unroll
    for (int ky = 0; ky < 3; ++ky)
#pragma unroll
        for (int kx = 0; kx < 3; ++kx)
#pragma unroll
            for (int ci = 0; ci < 3; ++ci) {
                float w = W[(ky * 3 + kx) * 96 + ci * 32 + co];
                a00 += patch[ky    ][kx    ][ci] * w;
                a01 += patch[ky    ][kx + 1][ci] * w;
                a10 += patch[ky + 1][kx    ][ci] * w;
                a11 += patch[ky + 1][kx + 1][ci] * w;
            }
    float mx = fmaxf(fmaxf(a00, a01), fmaxf(a10, a11));
    mx = fmaxf(mx, 0.f);   // relu commutes with max
    out[t] = (mx - m[co]) * rsqrtf(v[co] + EPS) * g[co] + bb[co];
}

// ---------------------------------------------------------------------------
// Kernel 2: conv2 (3x3, 32->64, SAME) + bias + relu + BN + 2x2 maxpool
// h1: [2048,16,16,32] -> h2: [2048,8,8,64]   (flatten matches reshape order)
// ---------------------------------------------------------------------------
__global__ __launch_bounds__(256) void k_conv2(
    const float* __restrict__ h1, const float* __restrict__ W,
    const float* __restrict__ bias,
    const float* __restrict__ g, const float* __restrict__ bb,
    const float* __restrict__ m, const float* __restrict__ v,
    float* __restrict__ out)
{
    int t = blockIdx.x * blockDim.x + threadIdx.x;   // 2048*8*8*64
    int co = t & 63;
    int px = (t >> 6) & 7;
    int py = (t >> 9) & 7;
    int b  = t >> 12;

    int y0 = 2 * py - 1, x0 = 2 * px - 1;
    int off[4][4];
#pragma unroll
    for (int r = 0; r < 4; ++r) {
        int y = y0 + r;
        bool yok = ((unsigned)y < 16u);
#pragma unroll
        for (int c = 0; c < 4; ++c) {
            int xx = x0 + c;
            bool ok = yok && ((unsigned)xx < 16u);
            off[r][c] = ok ? (((b * 16 + y) * 16 + xx) * 32) : -1;
        }
    }

    float bv = bias[co];
    float a00 = bv, a01 = bv, a10 = bv, a11 = bv;

    for (int ci = 0; ci < 32; ++ci) {
        float patch[4][4];
#pragma unroll
        for (int r = 0; r < 4; ++r)
#pragma unroll
            for (int c = 0; c < 4; ++c)
                patch[r][c] = (off[r][c] >= 0) ? h1[off[r][c] + ci] : 0.f;

        const float* wb = W + ci * 64 + co;
#pragma unroll
        for (int ky = 0; ky < 3; ++ky)
#pragma unroll
            for (int kx = 0; kx < 3; ++kx) {
                float w = wb[(ky * 3 + kx) * 2048];
                a00 += patch[ky    ][kx    ] * w;
                a01 += patch[ky    ][kx + 1] * w;
                a10 += patch[ky + 1][kx    ] * w;
                a11 += patch[ky + 1][kx + 1] * w;
            }
    }
    float mx = fmaxf(fmaxf(a00, a01), fmaxf(a10, a11));
    mx = fmaxf(mx, 0.f);
    out[t] = (mx - m[co]) * rsqrtf(v[co] + EPS) * g[co] + bb[co];
}

// ---------------------------------------------------------------------------
// Kernel 3: dense 4096 -> 128 + relu.  feats[b][j] = relu(h2[b,:] @ dW[:,j] + db[j])
// grid 256 (8 rows each), block 256: j = tid&127, bg = tid>>7 -> 4 rows each.
// LDS chunk transposed [kk][b] so the 4-row read is contiguous.
// ---------------------------------------------------------------------------
__global__ __launch_bounds__(256) void k_dense(
    const float* __restrict__ h2, const float* __restrict__ dW,
    const float* __restrict__ db, float* __restrict__ feats)
{
    __shared__ float lt[128][9];    // +1 pad on 8 to dodge write conflicts
    int tid  = threadIdx.x;
    int j    = tid & 127;
    int bg   = tid >> 7;            // 0 or 1
    int brow = blockIdx.x * 8;

    int bcol = tid >> 5;            // 0..7 (stage assignment)
    int kk0  = (tid & 31) * 4;

    float acc0 = 0.f, acc1 = 0.f, acc2 = 0.f, acc3 = 0.f;

    for (int k0 = 0; k0 < 4096; k0 += 128) {
        __syncthreads();
        const float4 hv = *(const float4*)(h2 + (long)(brow + bcol) * 4096 + k0 + kk0);
        lt[kk0 + 0][bcol] = hv.x;
        lt[kk0 + 1][bcol] = hv.y;
        lt[kk0 + 2][bcol] = hv.z;
        lt[kk0 + 3][bcol] = hv.w;
        __syncthreads();

        const float* dwp = dW + (long)k0 * 128 + j;
#pragma unroll 8
        for (int kk = 0; kk < 128; ++kk) {
            float w = dwp[kk * 128];
            const float* lp = &lt[kk][bg * 4];
            acc0 += lp[0] * w;
            acc1 += lp[1] * w;
            acc2 += lp[2] * w;
            acc3 += lp[3] * w;
        }
    }
    float bj = db[j];
    int b0 = brow + bg * 4;
    feats[(long)(b0 + 0) * 128 + j] = fmaxf(acc0 + bj, 0.f);
    feats[(long)(b0 + 1) * 128 + j] = fmaxf(acc1 + bj, 0.f);
    feats[(long)(b0 + 2) * 128 + j] = fmaxf(acc2 + bj, 0.f);
    feats[(long)(b0 + 3) * 128 + j] = fmaxf(acc3 + bj, 0.f);
}

// ---------------------------------------------------------------------------
// Kernel 4: router MLP + softmax.  one block (64 threads) per batch row.
// ---------------------------------------------------------------------------
__global__ __launch_bounds__(64) void k_router(
    const float* __restrict__ feats,
    const float* __restrict__ rW1, const float* __restrict__ rb1,
    const float* __restrict__ rW2, const float* __restrict__ rb2,
    float* __restrict__ probs)
{
    __shared__ float f[128];
    __shared__ float r1[64];
    __shared__ float lg[16];
    int b = blockIdx.x, tid = threadIdx.x;

    f[tid]      = feats[(long)b * 128 + tid];
    f[tid + 64] = feats[(long)b * 128 + 64 + tid];
    __syncthreads();

    float acc = rb1[tid];
#pragma unroll 8
    for (int d = 0; d < 128; ++d) acc += f[d] * rW1[d * 64 + tid];
    r1[tid] = fmaxf(acc, 0.f);
    __syncthreads();

    if (tid < 16) {
        float a = rb2[tid];
#pragma unroll 8
        for (int k = 0; k < 64; ++k) a += r1[k] * rW2[k * 16 + tid];
        lg[tid] = a;
    }
    __syncthreads();

    if (tid == 0) {
        float mx = lg[0];
#pragma unroll
        for (int i = 1; i < 16; ++i) mx = fmaxf(mx, lg[i]);
        float s = 0.f, e[16];
#pragma unroll
        for (int i = 0; i < 16; ++i) { e[i] = __expf(lg[i] - mx); s += e[i]; }
        float inv = 1.f / s;
#pragma unroll
        for (int i = 0; i < 16; ++i) probs[(long)b * 16 + i] = e[i] * inv;
    }
}

// ---------------------------------------------------------------------------
// Kernel 5: fused expert chain.  grid (16 experts, 128 b-tiles of 16), block 128.
// h1 = BN(relu(feats@eW1 + eb1)); h2e = relu(h1@eW2 + eb2); e3 = h2e@eW3 + eb3
// ---------------------------------------------------------------------------
__global__ __launch_bounds__(128) void k_expert(
    const float* __restrict__ feats,
    const float* __restrict__ eW1, const float* __restrict__ eb1,
    const float* __restrict__ g,  const float* __restrict__ bb,
    const float* __restrict__ m,  const float* __restrict__ v,
    const float* __restrict__ eW2, const float* __restrict__ eb2,
    const float* __restrict__ eW3, const float* __restrict__ eb3,
    float* __restrict__ e3out)
{
    int e    = blockIdx.x;   // 0..15
    int bt   = blockIdx.y;   // 0..127
    int tid  = threadIdx.x;  // 0..127
    int brow = bt * 16;

    __shared__ float fs[16][128];
    __shared__ float h1s[16][128];
    __shared__ float h2s[16][64];

#pragma unroll
    for (int i = 0; i < 16; ++i)
        fs[i][tid] = feats[(long)(brow + i) * 128 + tid];
    __syncthreads();

    // phase 1: h = tid, 16 rows
    {
        float acc[16];
        float bv = eb1[e * 128 + tid];
#pragma unroll
        for (int r = 0; r < 16; ++r) acc[r] = bv;
        const float* W = eW1 + (long)e * 128 * 128;   // [d][h]
        for (int d = 0; d < 128; ++d) {
            float w = W[d * 128 + tid];
#pragma unroll
            for (int r = 0; r < 16; ++r) acc[r] += fs[r][d] * w;
        }
        float gg  = g[e * 128 + tid];
        float bbv = bb[e * 128 + tid];
        float mm  = m[e * 128 + tid];
        float inv = rsqrtf(v[e * 128 + tid] + EPS);
#pragma unroll
        for (int r = 0; r < 16; ++r) {
            float xx = fmaxf(acc[r], 0.f);
            h1s[r][tid] = (xx - mm) * inv * gg + bbv;
        }
    }
    __syncthreads();

    // phase 2: k = tid&63, two groups of 8 rows
    {
        int k = tid & 63, bg = tid >> 6;
        float acc[8];
        float bv = eb2[e * 64 + k];
#pragma unroll
        for (int r = 0; r < 8; ++r) acc[r] = bv;
        const float* W = eW2 + (long)e * 128 * 64;    // [h][k]
        for (int d = 0; d < 128; ++d) {
            float w = W[d * 64 + k];
#pragma unroll
            for (int r = 0; r < 8; ++r) acc[r] += h1s[bg * 8 + r][d] * w;
        }
#pragma unroll
        for (int r = 0; r < 8; ++r) h2s[bg * 8 + r][k] = fmaxf(acc[r], 0.f);
    }
    __syncthreads();

    // phase 3: 160 outputs (16 rows x 10 classes)
    const float* W3 = eW3 + (long)e * 64 * 10;
    for (int t = tid; t < 160; t += 128) {
        int r = t / 10, c = t % 10;
        float acc = eb3[e * 10 + c];
#pragma unroll 8
        for (int k = 0; k < 64; ++k) acc += h2s[r][k] * W3[k * 10 + c];
        e3out[((long)e * 2048 + brow + r) * 10 + c] = acc;
    }
}

// ---------------------------------------------------------------------------
// Kernel 6: combine.  out[b][c] = sum_e probs[b][e] * e3[e][b][c]
// ---------------------------------------------------------------------------
__global__ __launch_bounds__(256) void k_combine(
    const float* __restrict__ e3, const float* __restrict__ probs,
    float* __restrict__ out)
{
    int t = blockIdx.x * blockDim.x + threadIdx.x;
    if (t >= 2048 * 10) return;
    int b = t / 10, c = t % 10;
    float acc = 0.f;
#pragma unroll
    for (int e = 0; e < 16; ++e)
        acc += probs[(long)b * 16 + e] * e3[((long)e * 2048 + b) * 10 + c];
    out[t] = acc;
}

// ---------------------------------------------------------------------------
extern "C" void kernel_launch(void* const* d_in, const int* in_sizes, int n_in,
                              void* d_out, int out_size, void* d_ws, size_t ws_size,
                              hipStream_t stream)
{
    const float* x    = (const float*)d_in[0];
    const float* cW1  = (const float*)d_in[1];
    const float* cb1  = (const float*)d_in[2];
    const float* bn1g = (const float*)d_in[3];
    const float* bn1b = (const float*)d_in[4];
    const float* bn1m = (const float*)d_in[5];
    const float* bn1v = (const float*)d_in[6];
    const float* cW2  = (const float*)d_in[7];
    const float* cb2  = (const float*)d_in[8];
    const float* bn2g = (const float*)d_in[9];
    const float* bn2b = (const float*)d_in[10];
    const float* bn2m = (const float*)d_in[11];
    const float* bn2v = (const float*)d_in[12];
    const float* dW   = (const float*)d_in[13];
    const float* db   = (const float*)d_in[14];
    const float* rW1  = (const float*)d_in[15];
    const float* rb1  = (const float*)d_in[16];
    const float* rW2  = (const float*)d_in[17];
    const float* rb2  = (const float*)d_in[18];
    const float* eW1  = (const float*)d_in[19];
    const float* eb1  = (const float*)d_in[20];
    const float* ebng = (const float*)d_in[21];
    const float* ebnb = (const float*)d_in[22];
    const float* ebnm = (const float*)d_in[23];
    const float* ebnv = (const float*)d_in[24];
    const float* eW2  = (const float*)d_in[25];
    const float* eb2  = (const float*)d_in[26];
    const float* eW3  = (const float*)d_in[27];
    const float* eb3  = (const float*)d_in[28];

    float* ws    = (float*)d_ws;
    float* h1    = ws;                     // 2048*16*16*32 = 16,777,216
    float* h2    = h1 + 16777216;          //  2048*8*8*64  =  8,388,608
    float* feats = h2 + 8388608;           //  2048*128     =    262,144
    float* probs = feats + 262144;         //  2048*16      =     32,768
    float* e3    = probs + 32768;          //  16*2048*10   =    327,680
    float* out   = (float*)d_out;          //  2048*10

    k_conv1<<<65536, 256, 0, stream>>>(x, cW1, cb1, bn1g, bn1b, bn1m, bn1v, h1);
    k_conv2<<<32768, 256, 0, stream>>>(h1, cW2, cb2, bn2g, bn2b, bn2m, bn2v, h2);
    k_dense<<<256, 256, 0, stream>>>(h2, dW, db, feats);
    k_router<<<2048, 64, 0, stream>>>(feats, rW1, rb1, rW2, rb2, probs);
    {
        dim3 grid(16, 128);
        k_expert<<<grid, 128, 0, stream>>>(feats, eW1, eb1, ebng, ebnb, ebnm, ebnv,
                                           eW2, eb2, eW3, eb3, e3);
    }
    k_combine<<<80, 256, 0, stream>>>(e3, probs, out);
}

// Round 2
// 411.123 us; speedup vs baseline: 2.6228x; 2.6228x over previous
//
#include <hip/hip_runtime.h>

#define EPS 1e-3f

typedef _Float16 half8 __attribute__((ext_vector_type(8)));
typedef _Float16 half4v __attribute__((ext_vector_type(4)));
typedef float f32x4 __attribute__((ext_vector_type(4)));

// ---------------------------------------------------------------------------
// Kernel 1: conv1 (3x3, 3->32, SAME) + bias + relu + BN + 2x2 maxpool
// x: [2048,32,32,3]  -> h1: [2048,16,16,32]
// ---------------------------------------------------------------------------
__global__ __launch_bounds__(256) void k_conv1(
    const float* __restrict__ x, const float* __restrict__ W,
    const float* __restrict__ bias,
    const float* __restrict__ g, const float* __restrict__ bb,
    const float* __restrict__ m, const float* __restrict__ v,
    float* __restrict__ out)
{
    int t = blockIdx.x * blockDim.x + threadIdx.x;   // 2048*16*16*32
    int co = t & 31;
    int px = (t >> 5) & 15;
    int py = (t >> 9) & 15;
    int b  = t >> 13;

    int y0 = 2 * py - 1, x0 = 2 * px - 1;
    float patch[4][4][3];
#pragma unroll
    for (int r = 0; r < 4; ++r) {
        int y = y0 + r;
        bool yok = ((unsigned)y < 32u);
#pragma unroll
        for (int c = 0; c < 4; ++c) {
            int xx = x0 + c;
            bool ok = yok && ((unsigned)xx < 32u);
            const float* p = x + (((long)b * 32 + y) * 32 + xx) * 3;
#pragma unroll
            for (int ci = 0; ci < 3; ++ci)
                patch[r][c][ci] = ok ? p[ci] : 0.f;
        }
    }

    float bv = bias[co];
    float a00 = bv, a01 = bv, a10 = bv, a11 = bv;
#pragma unroll
    for (int ky = 0; ky < 3; ++ky)
#pragma unroll
        for (int kx = 0; kx < 3; ++kx)
#pragma unroll
            for (int ci = 0; ci < 3; ++ci) {
                float w = W[(ky * 3 + kx) * 96 + ci * 32 + co];
                a00 += patch[ky    ][kx    ][ci] * w;
                a01 += patch[ky    ][kx + 1][ci] * w;
                a10 += patch[ky + 1][kx    ][ci] * w;
                a11 += patch[ky + 1][kx + 1][ci] * w;
            }
    float mx = fmaxf(fmaxf(a00, a01), fmaxf(a10, a11));
    mx = fmaxf(mx, 0.f);   // relu commutes with max
    out[t] = (mx - m[co]) * rsqrtf(v[co] + EPS) * g[co] + bb[co];
}

// ---------------------------------------------------------------------------
// Weight prep for conv2 MFMA: W [3][3][32][64] fp32 -> Wt [9][64][32] f16
// ---------------------------------------------------------------------------
__global__ __launch_bounds__(256) void k_wprep(
    const float* __restrict__ W, _Float16* __restrict__ Wt)
{
    int t = blockIdx.x * 256 + threadIdx.x;
    if (t >= 9 * 32 * 64) return;
    int co = t & 63;
    int rest = t >> 6;          // tap*32 + ci
    int ci = rest & 31, tap = rest >> 5;
    Wt[(tap * 64 + co) * 32 + ci] = (_Float16)W[t];
}

// ---------------------------------------------------------------------------
// Kernel 2: conv2 as implicit-GEMM f16 MFMA.
// One block per image. M = 256 pre-pool pixels, N = 64 co, K = 9 taps x 32 ci.
// A staged in LDS [18][18][40] f16 (zero halo, pad->16B-aligned b128 reads).
// B fragments read directly from global Wt (L2-resident).
// Epilogue: 2x2 maxpool + relu + BN -> h2 [2048,8,8,64] fp32.
// D layout: col = lane&15 (co), row = (lane>>4)*4 + reg (px).
// ---------------------------------------------------------------------------
__global__ __launch_bounds__(256) void k_conv2_mfma(
    const float* __restrict__ h1, const _Float16* __restrict__ Wt,
    const float* __restrict__ bias,
    const float* __restrict__ g, const float* __restrict__ bb,
    const float* __restrict__ m, const float* __restrict__ v,
    float* __restrict__ out)
{
    __shared__ __align__(16) _Float16 As[18][18][40];
    int tid = threadIdx.x;
    int b   = blockIdx.x;
    int w   = tid >> 6;         // wave 0..3
    int l   = tid & 63;
    int l15 = l & 15, lq = l >> 4;

    // zero the LDS (halo must be 0; pads never read but cheap to clear)
    {
        _Float16* flat = &As[0][0][0];
        for (int i = tid * 8; i < 18 * 18 * 40; i += 256 * 8)
            *(float4*)(flat + i) = make_float4(0.f, 0.f, 0.f, 0.f);
    }
    __syncthreads();

    // stage image: thread = pixel, 32 channels fp32 -> f16
    {
        int py = tid >> 4, px = tid & 15;
        const float* src = h1 + ((long)b * 256 + tid) * 32;
        _Float16* dst = &As[py + 1][px + 1][0];
#pragma unroll
        for (int i = 0; i < 8; ++i) {
            float4 f = *(const float4*)(src + i * 4);
            half4v hv = { (_Float16)f.x, (_Float16)f.y, (_Float16)f.z, (_Float16)f.w };
            *(half4v*)(dst + i * 4) = hv;
        }
    }

    // init accumulators with bias (broadcast over rows)
    f32x4 acc[4][4];
#pragma unroll
    for (int nf = 0; nf < 4; ++nf) {
        float bv = bias[nf * 16 + l15];
#pragma unroll
        for (int mf = 0; mf < 4; ++mf)
            acc[mf][nf] = (f32x4){ bv, bv, bv, bv };
    }
    __syncthreads();

    int row0 = 4 * w;          // wave's 4 pre-pool rows
#pragma unroll
    for (int tap = 0; tap < 9; ++tap) {
        int ky = tap / 3, kx = tap % 3;
        half8 bf[4];
        const _Float16* wb = Wt + ((long)(tap * 64 + l15)) * 32 + lq * 8;
#pragma unroll
        for (int nf = 0; nf < 4; ++nf)
            bf[nf] = *(const half8*)(wb + (long)nf * 16 * 32);
#pragma unroll
        for (int mf = 0; mf < 4; ++mf) {
            const _Float16* ap = &As[row0 + mf + ky][l15 + kx][lq * 8];
            half8 af = *(const half8*)ap;
#pragma unroll
            for (int nf = 0; nf < 4; ++nf)
                acc[mf][nf] = __builtin_amdgcn_mfma_f32_16x16x32_f16(
                    af, bf[nf], acc[mf][nf], 0, 0, 0);
        }
    }

    // epilogue: 2x2 maxpool + relu + BN
#pragma unroll
    for (int nf = 0; nf < 4; ++nf) {
        int co = nf * 16 + l15;
        float gg = g[co], bbv = bb[co], mm = m[co];
        float iv = rsqrtf(v[co] + EPS);
#pragma unroll
        for (int pr = 0; pr < 2; ++pr) {
            int prow = 2 * w + pr;           // pooled row 0..7
            f32x4 a0 = acc[2 * pr][nf];      // py = row0+2pr
            f32x4 a1 = acc[2 * pr + 1][nf];  // py = row0+2pr+1
            float p0 = fmaxf(fmaxf(a0[0], a0[1]), fmaxf(a1[0], a1[1]));
            float p1 = fmaxf(fmaxf(a0[2], a0[3]), fmaxf(a1[2], a1[3]));
            p0 = fmaxf(p0, 0.f);
            p1 = fmaxf(p1, 0.f);
            int ppx = lq * 2;
            long base = (((long)b * 8 + prow) * 8) * 64 + co;
            out[base + (long)(ppx    ) * 64] = (p0 - mm) * iv * gg + bbv;
            out[base + (long)(ppx + 1) * 64] = (p1 - mm) * iv * gg + bbv;
        }
    }
}

// ---------------------------------------------------------------------------
// Kernel 3: dense 4096 -> 128 + relu.
// ---------------------------------------------------------------------------
__global__ __launch_bounds__(256) void k_dense(
    const float* __restrict__ h2, const float* __restrict__ dW,
    const float* __restrict__ db, float* __restrict__ feats)
{
    __shared__ float lt[128][9];
    int tid  = threadIdx.x;
    int j    = tid & 127;
    int bg   = tid >> 7;
    int brow = blockIdx.x * 8;

    int bcol = tid >> 5;
    int kk0  = (tid & 31) * 4;

    float acc0 = 0.f, acc1 = 0.f, acc2 = 0.f, acc3 = 0.f;

    for (int k0 = 0; k0 < 4096; k0 += 128) {
        __syncthreads();
        const float4 hv = *(const float4*)(h2 + (long)(brow + bcol) * 4096 + k0 + kk0);
        lt[kk0 + 0][bcol] = hv.x;
        lt[kk0 + 1][bcol] = hv.y;
        lt[kk0 + 2][bcol] = hv.z;
        lt[kk0 + 3][bcol] = hv.w;
        __syncthreads();

        const float* dwp = dW + (long)k0 * 128 + j;
#pragma unroll 8
        for (int kk = 0; kk < 128; ++kk) {
            float w = dwp[kk * 128];
            const float* lp = &lt[kk][bg * 4];
            acc0 += lp[0] * w;
            acc1 += lp[1] * w;
            acc2 += lp[2] * w;
            acc3 += lp[3] * w;
        }
    }
    float bj = db[j];
    int b0 = brow + bg * 4;
    feats[(long)(b0 + 0) * 128 + j] = fmaxf(acc0 + bj, 0.f);
    feats[(long)(b0 + 1) * 128 + j] = fmaxf(acc1 + bj, 0.f);
    feats[(long)(b0 + 2) * 128 + j] = fmaxf(acc2 + bj, 0.f);
    feats[(long)(b0 + 3) * 128 + j] = fmaxf(acc3 + bj, 0.f);
}

// ---------------------------------------------------------------------------
// Kernel 4: router MLP + softmax.
// ---------------------------------------------------------------------------
__global__ __launch_bounds__(64) void k_router(
    const float* __restrict__ feats,
    const float* __restrict__ rW1, const float* __restrict__ rb1,
    const float* __restrict__ rW2, const float* __restrict__ rb2,
    float* __restrict__ probs)
{
    __shared__ float f[128];
    __shared__ float r1[64];
    __shared__ float lg[16];
    int b = blockIdx.x, tid = threadIdx.x;

    f[tid]      = feats[(long)b * 128 + tid];
    f[tid + 64] = feats[(long)b * 128 + 64 + tid];
    __syncthreads();

    float acc = rb1[tid];
#pragma unroll 8
    for (int d = 0; d < 128; ++d) acc += f[d] * rW1[d * 64 + tid];
    r1[tid] = fmaxf(acc, 0.f);
    __syncthreads();

    if (tid < 16) {
        float a = rb2[tid];
#pragma unroll 8
        for (int k = 0; k < 64; ++k) a += r1[k] * rW2[k * 16 + tid];
        lg[tid] = a;
    }
    __syncthreads();

    if (tid == 0) {
        float mx = lg[0];
#pragma unroll
        for (int i = 1; i < 16; ++i) mx = fmaxf(mx, lg[i]);
        float s = 0.f, e[16];
#pragma unroll
        for (int i = 0; i < 16; ++i) { e[i] = __expf(lg[i] - mx); s += e[i]; }
        float inv = 1.f / s;
#pragma unroll
        for (int i = 0; i < 16; ++i) probs[(long)b * 16 + i] = e[i] * inv;
    }
}

// ---------------------------------------------------------------------------
// Kernel 5: fused expert chain.
// ---------------------------------------------------------------------------
__global__ __launch_bounds__(128) void k_expert(
    const float* __restrict__ feats,
    const float* __restrict__ eW1, const float* __restrict__ eb1,
    const float* __restrict__ g,  const float* __restrict__ bb,
    const float* __restrict__ m,  const float* __restrict__ v,
    const float* __restrict__ eW2, const float* __restrict__ eb2,
    const float* __restrict__ eW3, const float* __restrict__ eb3,
    float* __restrict__ e3out)
{
    int e    = blockIdx.x;
    int bt   = blockIdx.y;
    int tid  = threadIdx.x;
    int brow = bt * 16;

    __shared__ float fs[16][128];
    __shared__ float h1s[16][128];
    __shared__ float h2s[16][64];

#pragma unroll
    for (int i = 0; i < 16; ++i)
        fs[i][tid] = feats[(long)(brow + i) * 128 + tid];
    __syncthreads();

    {
        float acc[16];
        float bv = eb1[e * 128 + tid];
#pragma unroll
        for (int r = 0; r < 16; ++r) acc[r] = bv;
        const float* W = eW1 + (long)e * 128 * 128;
        for (int d = 0; d < 128; ++d) {
            float w = W[d * 128 + tid];
#pragma unroll
            for (int r = 0; r < 16; ++r) acc[r] += fs[r][d] * w;
        }
        float gg  = g[e * 128 + tid];
        float bbv = bb[e * 128 + tid];
        float mm  = m[e * 128 + tid];
        float inv = rsqrtf(v[e * 128 + tid] + EPS);
#pragma unroll
        for (int r = 0; r < 16; ++r) {
            float xx = fmaxf(acc[r], 0.f);
            h1s[r][tid] = (xx - mm) * inv * gg + bbv;
        }
    }
    __syncthreads();

    {
        int k = tid & 63, bg = tid >> 6;
        float acc[8];
        float bv = eb2[e * 64 + k];
#pragma unroll
        for (int r = 0; r < 8; ++r) acc[r] = bv;
        const float* W = eW2 + (long)e * 128 * 64;
        for (int d = 0; d < 128; ++d) {
            float w = W[d * 64 + k];
#pragma unroll
            for (int r = 0; r < 8; ++r) acc[r] += h1s[bg * 8 + r][d] * w;
        }
#pragma unroll
        for (int r = 0; r < 8; ++r) h2s[bg * 8 + r][k] = fmaxf(acc[r], 0.f);
    }
    __syncthreads();

    const float* W3 = eW3 + (long)e * 64 * 10;
    for (int t = tid; t < 160; t += 128) {
        int r = t / 10, c = t % 10;
        float acc = eb3[e * 10 + c];
#pragma unroll 8
        for (int k = 0; k < 64; ++k) acc += h2s[r][k] * W3[k * 10 + c];
        e3out[((long)e * 2048 + brow + r) * 10 + c] = acc;
    }
}

// ---------------------------------------------------------------------------
// Kernel 6: combine.
// ---------------------------------------------------------------------------
__global__ __launch_bounds__(256) void k_combine(
    const float* __restrict__ e3, const float* __restrict__ probs,
    float* __restrict__ out)
{
    int t = blockIdx.x * blockDim.x + threadIdx.x;
    if (t >= 2048 * 10) return;
    int b = t / 10, c = t % 10;
    float acc = 0.f;
#pragma unroll
    for (int e = 0; e < 16; ++e)
        acc += probs[(long)b * 16 + e] * e3[((long)e * 2048 + b) * 10 + c];
    out[t] = acc;
}

// ---------------------------------------------------------------------------
extern "C" void kernel_launch(void* const* d_in, const int* in_sizes, int n_in,
                              void* d_out, int out_size, void* d_ws, size_t ws_size,
                              hipStream_t stream)
{
    const float* x    = (const float*)d_in[0];
    const float* cW1  = (const float*)d_in[1];
    const float* cb1  = (const float*)d_in[2];
    const float* bn1g = (const float*)d_in[3];
    const float* bn1b = (const float*)d_in[4];
    const float* bn1m = (const float*)d_in[5];
    const float* bn1v = (const float*)d_in[6];
    const float* cW2  = (const float*)d_in[7];
    const float* cb2  = (const float*)d_in[8];
    const float* bn2g = (const float*)d_in[9];
    const float* bn2b = (const float*)d_in[10];
    const float* bn2m = (const float*)d_in[11];
    const float* bn2v = (const float*)d_in[12];
    const float* dW   = (const float*)d_in[13];
    const float* db   = (const float*)d_in[14];
    const float* rW1  = (const float*)d_in[15];
    const float* rb1  = (const float*)d_in[16];
    const float* rW2  = (const float*)d_in[17];
    const float* rb2  = (const float*)d_in[18];
    const float* eW1  = (const float*)d_in[19];
    const float* eb1  = (const float*)d_in[20];
    const float* ebng = (const float*)d_in[21];
    const float* ebnb = (const float*)d_in[22];
    const float* ebnm = (const float*)d_in[23];
    const float* ebnv = (const float*)d_in[24];
    const float* eW2  = (const float*)d_in[25];
    const float* eb2  = (const float*)d_in[26];
    const float* eW3  = (const float*)d_in[27];
    const float* eb3  = (const float*)d_in[28];

    float* ws    = (float*)d_ws;
    float* h1    = ws;                     // 16,777,216 floats
    float* h2    = h1 + 16777216;          //  8,388,608
    float* feats = h2 + 8388608;           //    262,144
    float* probs = feats + 262144;         //     32,768
    float* e3    = probs + 32768;          //    327,680
    // Wt (f16, 18432 elems = 9216 floats) aliases the e3 region: used only by
    // k_conv2_mfma, which completes before k_expert writes e3. Deterministic
    // across graph replays (k_wprep rewrites it every launch).
    _Float16* Wt = (_Float16*)e3;
    float* out   = (float*)d_out;

    k_conv1<<<65536, 256, 0, stream>>>(x, cW1, cb1, bn1g, bn1b, bn1m, bn1v, h1);
    k_wprep<<<72, 256, 0, stream>>>(cW2, Wt);
    k_conv2_mfma<<<2048, 256, 0, stream>>>(h1, Wt, cb2, bn2g, bn2b, bn2m, bn2v, h2);
    k_dense<<<256, 256, 0, stream>>>(h2, dW, db, feats);
    k_router<<<2048, 64, 0, stream>>>(feats, rW1, rb1, rW2, rb2, probs);
    {
        dim3 grid(16, 128);
        k_expert<<<grid, 128, 0, stream>>>(feats, eW1, eb1, ebng, ebnb, ebnm, ebnv,
                                           eW2, eb2, eW3, eb3, e3);
    }
    k_combine<<<80, 256, 0, stream>>>(e3, probs, out);
}

// Round 3
// 289.423 us; speedup vs baseline: 3.7257x; 1.4205x over previous
//
#include <hip/hip_runtime.h>

#define EPS 1e-3f

typedef _Float16 half8 __attribute__((ext_vector_type(8)));
typedef _Float16 half4v __attribute__((ext_vector_type(4)));
typedef float f32x4 __attribute__((ext_vector_type(4)));

// ---------------------------------------------------------------------------
// Kernel 1: conv1 (3x3, 3->32, SAME) + bias + relu + BN + 2x2 maxpool
// x: [2048,32,32,3]  -> h1: [2048,16,16,32]
// ---------------------------------------------------------------------------
__global__ __launch_bounds__(256) void k_conv1(
    const float* __restrict__ x, const float* __restrict__ W,
    const float* __restrict__ bias,
    const float* __restrict__ g, const float* __restrict__ bb,
    const float* __restrict__ m, const float* __restrict__ v,
    float* __restrict__ out)
{
    int t = blockIdx.x * blockDim.x + threadIdx.x;   // 2048*16*16*32
    int co = t & 31;
    int px = (t >> 5) & 15;
    int py = (t >> 9) & 15;
    int b  = t >> 13;

    int y0 = 2 * py - 1, x0 = 2 * px - 1;
    float patch[4][4][3];
#pragma unroll
    for (int r = 0; r < 4; ++r) {
        int y = y0 + r;
        bool yok = ((unsigned)y < 32u);
#pragma unroll
        for (int c = 0; c < 4; ++c) {
            int xx = x0 + c;
            bool ok = yok && ((unsigned)xx < 32u);
            const float* p = x + (((long)b * 32 + y) * 32 + xx) * 3;
#pragma unroll
            for (int ci = 0; ci < 3; ++ci)
                patch[r][c][ci] = ok ? p[ci] : 0.f;
        }
    }

    float bv = bias[co];
    float a00 = bv, a01 = bv, a10 = bv, a11 = bv;
#pragma unroll
    for (int ky = 0; ky < 3; ++ky)
#pragma unroll
        for (int kx = 0; kx < 3; ++kx)
#pragma unroll
            for (int ci = 0; ci < 3; ++ci) {
                float w = W[(ky * 3 + kx) * 96 + ci * 32 + co];
                a00 += patch[ky    ][kx    ][ci] * w;
                a01 += patch[ky    ][kx + 1][ci] * w;
                a10 += patch[ky + 1][kx    ][ci] * w;
                a11 += patch[ky + 1][kx + 1][ci] * w;
            }
    float mx = fmaxf(fmaxf(a00, a01), fmaxf(a10, a11));
    mx = fmaxf(mx, 0.f);   // relu commutes with max
    out[t] = (mx - m[co]) * rsqrtf(v[co] + EPS) * g[co] + bb[co];
}

// ---------------------------------------------------------------------------
// Weight prep for conv2 MFMA: W [3][3][32][64] fp32 -> Wt [9][64][32] f16
// ---------------------------------------------------------------------------
__global__ __launch_bounds__(256) void k_wprep(
    const float* __restrict__ W, _Float16* __restrict__ Wt)
{
    int t = blockIdx.x * 256 + threadIdx.x;
    if (t >= 9 * 32 * 64) return;
    int co = t & 63;
    int rest = t >> 6;          // tap*32 + ci
    int ci = rest & 31, tap = rest >> 5;
    Wt[(tap * 64 + co) * 32 + ci] = (_Float16)W[t];
}

// ---------------------------------------------------------------------------
// Weight prep for dense MFMA: dW fp32 [4096][128] -> Wt2 f16 [128][4096]
// (n-major, k contiguous -> B-frag is one half8 load)
// ---------------------------------------------------------------------------
__global__ __launch_bounds__(256) void k_wprep2(
    const float* __restrict__ dW, _Float16* __restrict__ Wt2)
{
    __shared__ _Float16 lt[64][137];   // odd pad -> spread banks on col reads
    int kb  = blockIdx.x * 64;         // k tile
    int tid = threadIdx.x;

    int c = tid & 127, r2 = tid >> 7;  // 128 cols, 2 rows per iter
#pragma unroll
    for (int it = 0; it < 32; ++it) {
        int r = it * 2 + r2;
        lt[r][c] = (_Float16)dW[(long)(kb + r) * 128 + c];
    }
    __syncthreads();

#pragma unroll
    for (int it = 0; it < 4; ++it) {
        int chunk = it * 256 + tid;    // 1024 chunks of 8
        int n = chunk >> 3, kc = (chunk & 7) * 8;
        half8 v;
#pragma unroll
        for (int j = 0; j < 8; ++j) v[j] = lt[kc + j][n];
        *(half8*)(Wt2 + (long)n * 4096 + kb + kc) = v;
    }
}

// ---------------------------------------------------------------------------
// Kernel 2: conv2 as implicit-GEMM f16 MFMA.
// Epilogue: 2x2 maxpool + relu + BN -> h2 f16 [2048][4096] (= [B,8,8,64] flat)
// ---------------------------------------------------------------------------
__global__ __launch_bounds__(256) void k_conv2_mfma(
    const float* __restrict__ h1, const _Float16* __restrict__ Wt,
    const float* __restrict__ bias,
    const float* __restrict__ g, const float* __restrict__ bb,
    const float* __restrict__ m, const float* __restrict__ v,
    _Float16* __restrict__ out)
{
    __shared__ __align__(16) _Float16 As[18][18][40];
    int tid = threadIdx.x;
    int b   = blockIdx.x;
    int w   = tid >> 6;         // wave 0..3
    int l   = tid & 63;
    int l15 = l & 15, lq = l >> 4;

    {
        _Float16* flat = &As[0][0][0];
        for (int i = tid * 8; i < 18 * 18 * 40; i += 256 * 8)
            *(float4*)(flat + i) = make_float4(0.f, 0.f, 0.f, 0.f);
    }
    __syncthreads();

    {
        int py = tid >> 4, px = tid & 15;
        const float* src = h1 + ((long)b * 256 + tid) * 32;
        _Float16* dst = &As[py + 1][px + 1][0];
#pragma unroll
        for (int i = 0; i < 8; ++i) {
            float4 f = *(const float4*)(src + i * 4);
            half4v hv = { (_Float16)f.x, (_Float16)f.y, (_Float16)f.z, (_Float16)f.w };
            *(half4v*)(dst + i * 4) = hv;
        }
    }

    f32x4 acc[4][4];
#pragma unroll
    for (int nf = 0; nf < 4; ++nf) {
        float bv = bias[nf * 16 + l15];
#pragma unroll
        for (int mf = 0; mf < 4; ++mf)
            acc[mf][nf] = (f32x4){ bv, bv, bv, bv };
    }
    __syncthreads();

    int row0 = 4 * w;
#pragma unroll
    for (int tap = 0; tap < 9; ++tap) {
        int ky = tap / 3, kx = tap % 3;
        half8 bf[4];
        const _Float16* wb = Wt + ((long)(tap * 64 + l15)) * 32 + lq * 8;
#pragma unroll
        for (int nf = 0; nf < 4; ++nf)
            bf[nf] = *(const half8*)(wb + (long)nf * 16 * 32);
#pragma unroll
        for (int mf = 0; mf < 4; ++mf) {
            const _Float16* ap = &As[row0 + mf + ky][l15 + kx][lq * 8];
            half8 af = *(const half8*)ap;
#pragma unroll
            for (int nf = 0; nf < 4; ++nf)
                acc[mf][nf] = __builtin_amdgcn_mfma_f32_16x16x32_f16(
                    af, bf[nf], acc[mf][nf], 0, 0, 0);
        }
    }

#pragma unroll
    for (int nf = 0; nf < 4; ++nf) {
        int co = nf * 16 + l15;
        float gg = g[co], bbv = bb[co], mm = m[co];
        float iv = rsqrtf(v[co] + EPS);
#pragma unroll
        for (int pr = 0; pr < 2; ++pr) {
            int prow = 2 * w + pr;
            f32x4 a0 = acc[2 * pr][nf];
            f32x4 a1 = acc[2 * pr + 1][nf];
            float p0 = fmaxf(fmaxf(a0[0], a0[1]), fmaxf(a1[0], a1[1]));
            float p1 = fmaxf(fmaxf(a0[2], a0[3]), fmaxf(a1[2], a1[3]));
            p0 = fmaxf(p0, 0.f);
            p1 = fmaxf(p1, 0.f);
            int ppx = lq * 2;
            long base = (((long)b * 8 + prow) * 8) * 64 + co;
            out[base + (long)(ppx    ) * 64] = (_Float16)((p0 - mm) * iv * gg + bbv);
            out[base + (long)(ppx + 1) * 64] = (_Float16)((p1 - mm) * iv * gg + bbv);
        }
    }
}

// ---------------------------------------------------------------------------
// Kernel 3: dense 4096 -> 128 + relu as f16 MFMA.
// Grid 128 blocks: block = 16-row batch tile, wave = 32-col n slice.
// A staged in LDS [16][264] (+8 f16 pad), B-frags direct from L2-resident Wt2.
// ---------------------------------------------------------------------------
__global__ __launch_bounds__(256) void k_dense_mfma(
    const _Float16* __restrict__ h2f, const _Float16* __restrict__ Wt2,
    const float* __restrict__ db, float* __restrict__ feats)
{
    __shared__ __align__(16) _Float16 As[16][264];
    int tid = threadIdx.x;
    int w = tid >> 6, l = tid & 63;
    int l15 = l & 15, lq = l >> 4;
    int brow = blockIdx.x * 16;
    int n0 = w * 32;

    f32x4 acc[2];
#pragma unroll
    for (int nf = 0; nf < 2; ++nf) {
        float bv = db[n0 + nf * 16 + l15];
        acc[nf] = (f32x4){ bv, bv, bv, bv };
    }

    int srow = tid >> 4, sc = (tid & 15) * 16;
    for (int k0 = 0; k0 < 4096; k0 += 256) {
        __syncthreads();
        const _Float16* src = h2f + (long)(brow + srow) * 4096 + k0 + sc;
        half8 v0 = *(const half8*)src;
        half8 v1 = *(const half8*)(src + 8);
        *(half8*)(&As[srow][sc])     = v0;
        *(half8*)(&As[srow][sc + 8]) = v1;
        __syncthreads();
#pragma unroll
        for (int kk = 0; kk < 256; kk += 32) {
            half8 af = *(const half8*)(&As[l15][kk + lq * 8]);
#pragma unroll
            for (int nf = 0; nf < 2; ++nf) {
                half8 bf = *(const half8*)(Wt2 + (long)(n0 + nf * 16 + l15) * 4096
                                           + k0 + kk + lq * 8);
                acc[nf] = __builtin_amdgcn_mfma_f32_16x16x32_f16(af, bf, acc[nf], 0, 0, 0);
            }
        }
    }

#pragma unroll
    for (int nf = 0; nf < 2; ++nf) {
        int n = n0 + nf * 16 + l15;
#pragma unroll
        for (int reg = 0; reg < 4; ++reg) {
            int b = brow + lq * 4 + reg;
            feats[(long)b * 128 + n] = fmaxf(acc[nf][reg], 0.f);
        }
    }
}

// ---------------------------------------------------------------------------
// Kernel 4: router MLP + softmax.
// ---------------------------------------------------------------------------
__global__ __launch_bounds__(64) void k_router(
    const float* __restrict__ feats,
    const float* __restrict__ rW1, const float* __restrict__ rb1,
    const float* __restrict__ rW2, const float* __restrict__ rb2,
    float* __restrict__ probs)
{
    __shared__ float f[128];
    __shared__ float r1[64];
    __shared__ float lg[16];
    int b = blockIdx.x, tid = threadIdx.x;

    f[tid]      = feats[(long)b * 128 + tid];
    f[tid + 64] = feats[(long)b * 128 + 64 + tid];
    __syncthreads();

    float acc = rb1[tid];
#pragma unroll 8
    for (int d = 0; d < 128; ++d) acc += f[d] * rW1[d * 64 + tid];
    r1[tid] = fmaxf(acc, 0.f);
    __syncthreads();

    if (tid < 16) {
        float a = rb2[tid];
#pragma unroll 8
        for (int k = 0; k < 64; ++k) a += r1[k] * rW2[k * 16 + tid];
        lg[tid] = a;
    }
    __syncthreads();

    if (tid == 0) {
        float mx = lg[0];
#pragma unroll
        for (int i = 1; i < 16; ++i) mx = fmaxf(mx, lg[i]);
        float s = 0.f, e[16];
#pragma unroll
        for (int i = 0; i < 16; ++i) { e[i] = __expf(lg[i] - mx); s += e[i]; }
        float inv = 1.f / s;
#pragma unroll
        for (int i = 0; i < 16; ++i) probs[(long)b * 16 + i] = e[i] * inv;
    }
}

// ---------------------------------------------------------------------------
// Kernel 5: fused expert chain.
// ---------------------------------------------------------------------------
__global__ __launch_bounds__(128) void k_expert(
    const float* __restrict__ feats,
    const float* __restrict__ eW1, const float* __restrict__ eb1,
    const float* __restrict__ g,  const float* __restrict__ bb,
    const float* __restrict__ m,  const float* __restrict__ v,
    const float* __restrict__ eW2, const float* __restrict__ eb2,
    const float* __restrict__ eW3, const float* __restrict__ eb3,
    float* __restrict__ e3out)
{
    int e    = blockIdx.x;
    int bt   = blockIdx.y;
    int tid  = threadIdx.x;
    int brow = bt * 16;

    __shared__ float fs[16][128];
    __shared__ float h1s[16][128];
    __shared__ float h2s[16][64];

#pragma unroll
    for (int i = 0; i < 16; ++i)
        fs[i][tid] = feats[(long)(brow + i) * 128 + tid];
    __syncthreads();

    {
        float acc[16];
        float bv = eb1[e * 128 + tid];
#pragma unroll
        for (int r = 0; r < 16; ++r) acc[r] = bv;
        const float* W = eW1 + (long)e * 128 * 128;
        for (int d = 0; d < 128; ++d) {
            float w = W[d * 128 + tid];
#pragma unroll
            for (int r = 0; r < 16; ++r) acc[r] += fs[r][d] * w;
        }
        float gg  = g[e * 128 + tid];
        float bbv = bb[e * 128 + tid];
        float mm  = m[e * 128 + tid];
        float inv = rsqrtf(v[e * 128 + tid] + EPS);
#pragma unroll
        for (int r = 0; r < 16; ++r) {
            float xx = fmaxf(acc[r], 0.f);
            h1s[r][tid] = (xx - mm) * inv * gg + bbv;
        }
    }
    __syncthreads();

    {
        int k = tid & 63, bg = tid >> 6;
        float acc[8];
        float bv = eb2[e * 64 + k];
#pragma unroll
        for (int r = 0; r < 8; ++r) acc[r] = bv;
        const float* W = eW2 + (long)e * 128 * 64;
        for (int d = 0; d < 128; ++d) {
            float w = W[d * 64 + k];
#pragma unroll
            for (int r = 0; r < 8; ++r) acc[r] += h1s[bg * 8 + r][d] * w;
        }
#pragma unroll
        for (int r = 0; r < 8; ++r) h2s[bg * 8 + r][k] = fmaxf(acc[r], 0.f);
    }
    __syncthreads();

    const float* W3 = eW3 + (long)e * 64 * 10;
    for (int t = tid; t < 160; t += 128) {
        int r = t / 10, c = t % 10;
        float acc = eb3[e * 10 + c];
#pragma unroll 8
        for (int k = 0; k < 64; ++k) acc += h2s[r][k] * W3[k * 10 + c];
        e3out[((long)e * 2048 + brow + r) * 10 + c] = acc;
    }
}

// ---------------------------------------------------------------------------
// Kernel 6: combine.
// ---------------------------------------------------------------------------
__global__ __launch_bounds__(256) void k_combine(
    const float* __restrict__ e3, const float* __restrict__ probs,
    float* __restrict__ out)
{
    int t = blockIdx.x * blockDim.x + threadIdx.x;
    if (t >= 2048 * 10) return;
    int b = t / 10, c = t % 10;
    float acc = 0.f;
#pragma unroll
    for (int e = 0; e < 16; ++e)
        acc += probs[(long)b * 16 + e] * e3[((long)e * 2048 + b) * 10 + c];
    out[t] = acc;
}

// ---------------------------------------------------------------------------
extern "C" void kernel_launch(void* const* d_in, const int* in_sizes, int n_in,
                              void* d_out, int out_size, void* d_ws, size_t ws_size,
                              hipStream_t stream)
{
    const float* x    = (const float*)d_in[0];
    const float* cW1  = (const float*)d_in[1];
    const float* cb1  = (const float*)d_in[2];
    const float* bn1g = (const float*)d_in[3];
    const float* bn1b = (const float*)d_in[4];
    const float* bn1m = (const float*)d_in[5];
    const float* bn1v = (const float*)d_in[6];
    const float* cW2  = (const float*)d_in[7];
    const float* cb2  = (const float*)d_in[8];
    const float* bn2g = (const float*)d_in[9];
    const float* bn2b = (const float*)d_in[10];
    const float* bn2m = (const float*)d_in[11];
    const float* bn2v = (const float*)d_in[12];
    const float* dW   = (const float*)d_in[13];
    const float* db   = (const float*)d_in[14];
    const float* rW1  = (const float*)d_in[15];
    const float* rb1  = (const float*)d_in[16];
    const float* rW2  = (const float*)d_in[17];
    const float* rb2  = (const float*)d_in[18];
    const float* eW1  = (const float*)d_in[19];
    const float* eb1  = (const float*)d_in[20];
    const float* ebng = (const float*)d_in[21];
    const float* ebnb = (const float*)d_in[22];
    const float* ebnm = (const float*)d_in[23];
    const float* ebnv = (const float*)d_in[24];
    const float* eW2  = (const float*)d_in[25];
    const float* eb2  = (const float*)d_in[26];
    const float* eW3  = (const float*)d_in[27];
    const float* eb3  = (const float*)d_in[28];

    float* ws    = (float*)d_ws;
    float* h1    = ws;                     // 16,777,216 floats
    float* h2reg = h1 + 16777216;          //  8,388,608 float slots
    _Float16* h2f = (_Float16*)h2reg;      //  uses first half (16 MB) as f16
    _Float16* Wt2 = (_Float16*)(h2reg + 4194304);  // 524,288 f16 in 2nd half
    float* feats = h2reg + 8388608;        //    262,144
    float* probs = feats + 262144;         //     32,768
    float* e3    = probs + 32768;          //    327,680
    // Wt (conv2 weights f16, 18432 elems) aliases e3: consumed before k_expert.
    _Float16* Wt = (_Float16*)e3;
    float* out   = (float*)d_out;

    k_conv1<<<65536, 256, 0, stream>>>(x, cW1, cb1, bn1g, bn1b, bn1m, bn1v, h1);
    k_wprep<<<72, 256, 0, stream>>>(cW2, Wt);
    k_wprep2<<<64, 256, 0, stream>>>(dW, Wt2);
    k_conv2_mfma<<<2048, 256, 0, stream>>>(h1, Wt, cb2, bn2g, bn2b, bn2m, bn2v, h2f);
    k_dense_mfma<<<128, 256, 0, stream>>>(h2f, Wt2, db, feats);
    k_router<<<2048, 64, 0, stream>>>(feats, rW1, rb1, rW2, rb2, probs);
    {
        dim3 grid(16, 128);
        k_expert<<<grid, 128, 0, stream>>>(feats, eW1, eb1, ebng, ebnb, ebnm, ebnv,
                                           eW2, eb2, eW3, eb3, e3);
    }
    k_combine<<<80, 256, 0, stream>>>(e3, probs, out);
}

// Round 4
// 153.033 us; speedup vs baseline: 7.0462x; 1.8912x over previous
//
#include <hip/hip_runtime.h>

#define EPS 1e-3f

typedef _Float16 half8 __attribute__((ext_vector_type(8)));
typedef _Float16 half4v __attribute__((ext_vector_type(4)));
typedef float f32x4 __attribute__((ext_vector_type(4)));

// ---------------------------------------------------------------------------
// Weight prep conv1: W [3][3][3][32] fp32 -> Wt1 [3(ky)][32(co)][32(k)] f16
// k = kx*4 + ci, kx 0..7, ci 0..3;  zero for kx>=3 or ci==3.
// ---------------------------------------------------------------------------
__global__ __launch_bounds__(128) void k_wprep1(
    const float* __restrict__ W, _Float16* __restrict__ Wt1)
{
    int t = threadIdx.x + blockIdx.x * 128;
    if (t >= 3072) return;
    int k = t & 31, co = (t >> 5) & 31, ky = t >> 10;
    int kx = k >> 2, ci = k & 3;
    float val = (kx < 3 && ci < 3) ? W[((ky * 3 + kx) * 3 + ci) * 32 + co] : 0.f;
    Wt1[t] = (_Float16)val;
}

// ---------------------------------------------------------------------------
// Kernel 1: conv1 as implicit-GEMM f16 MFMA. One block per image.
// M = 1024 pre-pool pixels, N = 32 co, K = 32 (kx0..7 x ci4) per ky, 3 ky.
// A in LDS [34][40][4] f16 (halo zeros). Epilogue: pool+relu+BN -> h1 f16.
// ---------------------------------------------------------------------------
__global__ __launch_bounds__(256) void k_conv1_mfma(
    const float* __restrict__ x, const _Float16* __restrict__ Wt1,
    const float* __restrict__ bias,
    const float* __restrict__ g, const float* __restrict__ bb,
    const float* __restrict__ m, const float* __restrict__ v,
    _Float16* __restrict__ out)
{
    __shared__ __align__(16) _Float16 As[34][40][4];
    int tid = threadIdx.x;
    int b = blockIdx.x;
    int w = tid >> 6, l = tid & 63;
    int l15 = l & 15, lq = l >> 4;

    // zero LDS (halo + ci pad)
    {
        float4 z = make_float4(0.f, 0.f, 0.f, 0.f);
        float4* flat = (float4*)&As[0][0][0];
        for (int i = tid; i < 680; i += 256) flat[i] = z;
    }
    __syncthreads();

    // stage 4 pixels per thread (12 contiguous floats = 3 float4)
    {
        int y = tid >> 3, x0 = (tid & 7) * 4;
        const float* src = x + ((long)b * 1024 + y * 32 + x0) * 3;
        float4 f0 = *(const float4*)(src);
        float4 f1 = *(const float4*)(src + 4);
        float4 f2 = *(const float4*)(src + 8);
        half4v h0 = { (_Float16)f0.x, (_Float16)f0.y, (_Float16)f0.z, (_Float16)0.f };
        half4v h1 = { (_Float16)f0.w, (_Float16)f1.x, (_Float16)f1.y, (_Float16)0.f };
        half4v h2 = { (_Float16)f1.z, (_Float16)f1.w, (_Float16)f2.x, (_Float16)0.f };
        half4v h3 = { (_Float16)f2.y, (_Float16)f2.z, (_Float16)f2.w, (_Float16)0.f };
        *(half4v*)&As[y + 1][x0 + 1][0] = h0;
        *(half4v*)&As[y + 1][x0 + 2][0] = h1;
        *(half4v*)&As[y + 1][x0 + 3][0] = h2;
        *(half4v*)&As[y + 1][x0 + 4][0] = h3;
    }

    // preload B fragments + BN constants
    half8 bf[3][2];
#pragma unroll
    for (int ky = 0; ky < 3; ++ky)
#pragma unroll
        for (int nf = 0; nf < 2; ++nf)
            bf[ky][nf] = *(const half8*)(Wt1 + (ky * 32 + nf * 16 + l15) * 32 + lq * 8);

    float bv[2], gg[2], iv[2], mm[2], bbv[2];
#pragma unroll
    for (int nf = 0; nf < 2; ++nf) {
        int co = nf * 16 + l15;
        bv[nf] = bias[co]; gg[nf] = g[co]; bbv[nf] = bb[co]; mm[nf] = m[co];
        iv[nf] = rsqrtf(v[co] + EPS);
    }
    __syncthreads();

    int y0 = w * 8;
#pragma unroll
    for (int pr = 0; pr < 4; ++pr) {
        int ya = y0 + 2 * pr;     // rows ya, ya+1 pool together
        f32x4 acc[2][2][2];       // [row r][x-half h][nf]
#pragma unroll
        for (int r = 0; r < 2; ++r)
#pragma unroll
            for (int h = 0; h < 2; ++h)
#pragma unroll
                for (int nf = 0; nf < 2; ++nf)
                    acc[r][h][nf] = (f32x4){ bv[nf], bv[nf], bv[nf], bv[nf] };

#pragma unroll
        for (int ky = 0; ky < 3; ++ky)
#pragma unroll
            for (int r = 0; r < 2; ++r)
#pragma unroll
                for (int h = 0; h < 2; ++h) {
                    const _Float16* ap = &As[ya + r + ky][h * 16 + l15 + 2 * lq][0];
                    half4v a0 = *(const half4v*)ap;
                    half4v a1 = *(const half4v*)(ap + 4);
                    half8 af = __builtin_shufflevector(a0, a1, 0, 1, 2, 3, 4, 5, 6, 7);
#pragma unroll
                    for (int nf = 0; nf < 2; ++nf)
                        acc[r][h][nf] = __builtin_amdgcn_mfma_f32_16x16x32_f16(
                            af, bf[ky][nf], acc[r][h][nf], 0, 0, 0);
                }

        int py = w * 4 + pr;
#pragma unroll
        for (int h = 0; h < 2; ++h)
#pragma unroll
            for (int nf = 0; nf < 2; ++nf) {
                f32x4 aA = acc[0][h][nf], aB = acc[1][h][nf];
                float p0 = fmaxf(fmaxf(aA[0], aA[1]), fmaxf(aB[0], aB[1]));
                float p1 = fmaxf(fmaxf(aA[2], aA[3]), fmaxf(aB[2], aB[3]));
                p0 = fmaxf(p0, 0.f); p1 = fmaxf(p1, 0.f);
                p0 = (p0 - mm[nf]) * iv[nf] * gg[nf] + bbv[nf];
                p1 = (p1 - mm[nf]) * iv[nf] * gg[nf] + bbv[nf];
                int px = h * 8 + lq * 2;
                int co = nf * 16 + l15;
                long base = (((long)b * 16 + py) * 16 + px) * 32 + co;
                out[base]      = (_Float16)p0;
                out[base + 32] = (_Float16)p1;
            }
    }
}

// ---------------------------------------------------------------------------
// Weight prep for conv2 MFMA: W [3][3][32][64] fp32 -> Wt [9][64][32] f16
// ---------------------------------------------------------------------------
__global__ __launch_bounds__(256) void k_wprep(
    const float* __restrict__ W, _Float16* __restrict__ Wt)
{
    int t = blockIdx.x * 256 + threadIdx.x;
    if (t >= 9 * 32 * 64) return;
    int co = t & 63;
    int rest = t >> 6;          // tap*32 + ci
    int ci = rest & 31, tap = rest >> 5;
    Wt[(tap * 64 + co) * 32 + ci] = (_Float16)W[t];
}

// ---------------------------------------------------------------------------
// Weight prep for dense MFMA: dW fp32 [4096][128] -> Wt2 f16 [128][4096]
// ---------------------------------------------------------------------------
__global__ __launch_bounds__(256) void k_wprep2(
    const float* __restrict__ dW, _Float16* __restrict__ Wt2)
{
    __shared__ _Float16 lt[64][137];
    int kb  = blockIdx.x * 64;
    int tid = threadIdx.x;

    int c = tid & 127, r2 = tid >> 7;
#pragma unroll
    for (int it = 0; it < 32; ++it) {
        int r = it * 2 + r2;
        lt[r][c] = (_Float16)dW[(long)(kb + r) * 128 + c];
    }
    __syncthreads();

#pragma unroll
    for (int it = 0; it < 4; ++it) {
        int chunk = it * 256 + tid;
        int n = chunk >> 3, kc = (chunk & 7) * 8;
        half8 v;
#pragma unroll
        for (int j = 0; j < 8; ++j) v[j] = lt[kc + j][n];
        *(half8*)(Wt2 + (long)n * 4096 + kb + kc) = v;
    }
}

// ---------------------------------------------------------------------------
// Kernel 2: conv2 as implicit-GEMM f16 MFMA (input h1 f16 now).
// Epilogue: 2x2 maxpool + relu + BN -> h2 f16 [2048][4096]
// ---------------------------------------------------------------------------
__global__ __launch_bounds__(256) void k_conv2_mfma(
    const _Float16* __restrict__ h1f, const _Float16* __restrict__ Wt,
    const float* __restrict__ bias,
    const float* __restrict__ g, const float* __restrict__ bb,
    const float* __restrict__ m, const float* __restrict__ v,
    _Float16* __restrict__ out)
{
    __shared__ __align__(16) _Float16 As[18][18][40];
    int tid = threadIdx.x;
    int b   = blockIdx.x;
    int w   = tid >> 6;
    int l   = tid & 63;
    int l15 = l & 15, lq = l >> 4;

    {
        _Float16* flat = &As[0][0][0];
        for (int i = tid * 8; i < 18 * 18 * 40; i += 256 * 8)
            *(float4*)(flat + i) = make_float4(0.f, 0.f, 0.f, 0.f);
    }
    __syncthreads();

    {
        const _Float16* src = h1f + ((long)b * 256 + tid) * 32;
        _Float16* dst = &As[(tid >> 4) + 1][(tid & 15) + 1][0];
#pragma unroll
        for (int i = 0; i < 4; ++i)
            *(half8*)(dst + i * 8) = *(const half8*)(src + i * 8);
    }

    f32x4 acc[4][4];
#pragma unroll
    for (int nf = 0; nf < 4; ++nf) {
        float bv = bias[nf * 16 + l15];
#pragma unroll
        for (int mf = 0; mf < 4; ++mf)
            acc[mf][nf] = (f32x4){ bv, bv, bv, bv };
    }
    __syncthreads();

    int row0 = 4 * w;
#pragma unroll
    for (int tap = 0; tap < 9; ++tap) {
        int ky = tap / 3, kx = tap % 3;
        half8 bf[4];
        const _Float16* wb = Wt + ((long)(tap * 64 + l15)) * 32 + lq * 8;
#pragma unroll
        for (int nf = 0; nf < 4; ++nf)
            bf[nf] = *(const half8*)(wb + (long)nf * 16 * 32);
#pragma unroll
        for (int mf = 0; mf < 4; ++mf) {
            const _Float16* ap = &As[row0 + mf + ky][l15 + kx][lq * 8];
            half8 af = *(const half8*)ap;
#pragma unroll
            for (int nf = 0; nf < 4; ++nf)
                acc[mf][nf] = __builtin_amdgcn_mfma_f32_16x16x32_f16(
                    af, bf[nf], acc[mf][nf], 0, 0, 0);
        }
    }

#pragma unroll
    for (int nf = 0; nf < 4; ++nf) {
        int co = nf * 16 + l15;
        float gg = g[co], bbv = bb[co], mm = m[co];
        float iv = rsqrtf(v[co] + EPS);
#pragma unroll
        for (int pr = 0; pr < 2; ++pr) {
            int prow = 2 * w + pr;
            f32x4 a0 = acc[2 * pr][nf];
            f32x4 a1 = acc[2 * pr + 1][nf];
            float p0 = fmaxf(fmaxf(a0[0], a0[1]), fmaxf(a1[0], a1[1]));
            float p1 = fmaxf(fmaxf(a0[2], a0[3]), fmaxf(a1[2], a1[3]));
            p0 = fmaxf(p0, 0.f);
            p1 = fmaxf(p1, 0.f);
            int ppx = lq * 2;
            long base = (((long)b * 8 + prow) * 8) * 64 + co;
            out[base + (long)(ppx    ) * 64] = (_Float16)((p0 - mm) * iv * gg + bbv);
            out[base + (long)(ppx + 1) * 64] = (_Float16)((p1 - mm) * iv * gg + bbv);
        }
    }
}

// ---------------------------------------------------------------------------
// Kernel 3: dense 4096 -> 128 + relu as f16 MFMA.
// ---------------------------------------------------------------------------
__global__ __launch_bounds__(256) void k_dense_mfma(
    const _Float16* __restrict__ h2f, const _Float16* __restrict__ Wt2,
    const float* __restrict__ db, float* __restrict__ feats)
{
    __shared__ __align__(16) _Float16 As[16][264];
    int tid = threadIdx.x;
    int w = tid >> 6, l = tid & 63;
    int l15 = l & 15, lq = l >> 4;
    int brow = blockIdx.x * 16;
    int n0 = w * 32;

    f32x4 acc[2];
#pragma unroll
    for (int nf = 0; nf < 2; ++nf) {
        float bv = db[n0 + nf * 16 + l15];
        acc[nf] = (f32x4){ bv, bv, bv, bv };
    }

    int srow = tid >> 4, sc = (tid & 15) * 16;
    for (int k0 = 0; k0 < 4096; k0 += 256) {
        __syncthreads();
        const _Float16* src = h2f + (long)(brow + srow) * 4096 + k0 + sc;
        half8 v0 = *(const half8*)src;
        half8 v1 = *(const half8*)(src + 8);
        *(half8*)(&As[srow][sc])     = v0;
        *(half8*)(&As[srow][sc + 8]) = v1;
        __syncthreads();
#pragma unroll
        for (int kk = 0; kk < 256; kk += 32) {
            half8 af = *(const half8*)(&As[l15][kk + lq * 8]);
#pragma unroll
            for (int nf = 0; nf < 2; ++nf) {
                half8 bf = *(const half8*)(Wt2 + (long)(n0 + nf * 16 + l15) * 4096
                                           + k0 + kk + lq * 8);
                acc[nf] = __builtin_amdgcn_mfma_f32_16x16x32_f16(af, bf, acc[nf], 0, 0, 0);
            }
        }
    }

#pragma unroll
    for (int nf = 0; nf < 2; ++nf) {
        int n = n0 + nf * 16 + l15;
#pragma unroll
        for (int reg = 0; reg < 4; ++reg) {
            int b = brow + lq * 4 + reg;
            feats[(long)b * 128 + n] = fmaxf(acc[nf][reg], 0.f);
        }
    }
}

// ---------------------------------------------------------------------------
// Kernel 4: router MLP + softmax.
// ---------------------------------------------------------------------------
__global__ __launch_bounds__(64) void k_router(
    const float* __restrict__ feats,
    const float* __restrict__ rW1, const float* __restrict__ rb1,
    const float* __restrict__ rW2, const float* __restrict__ rb2,
    float* __restrict__ probs)
{
    __shared__ float f[128];
    __shared__ float r1[64];
    __shared__ float lg[16];
    int b = blockIdx.x, tid = threadIdx.x;

    f[tid]      = feats[(long)b * 128 + tid];
    f[tid + 64] = feats[(long)b * 128 + 64 + tid];
    __syncthreads();

    float acc = rb1[tid];
#pragma unroll 8
    for (int d = 0; d < 128; ++d) acc += f[d] * rW1[d * 64 + tid];
    r1[tid] = fmaxf(acc, 0.f);
    __syncthreads();

    if (tid < 16) {
        float a = rb2[tid];
#pragma unroll 8
        for (int k = 0; k < 64; ++k) a += r1[k] * rW2[k * 16 + tid];
        lg[tid] = a;
    }
    __syncthreads();

    if (tid == 0) {
        float mx = lg[0];
#pragma unroll
        for (int i = 1; i < 16; ++i) mx = fmaxf(mx, lg[i]);
        float s = 0.f, e[16];
#pragma unroll
        for (int i = 0; i < 16; ++i) { e[i] = __expf(lg[i] - mx); s += e[i]; }
        float inv = 1.f / s;
#pragma unroll
        for (int i = 0; i < 16; ++i) probs[(long)b * 16 + i] = e[i] * inv;
    }
}

// ---------------------------------------------------------------------------
// Kernel 5: fused expert chain.
// ---------------------------------------------------------------------------
__global__ __launch_bounds__(128) void k_expert(
    const float* __restrict__ feats,
    const float* __restrict__ eW1, const float* __restrict__ eb1,
    const float* __restrict__ g,  const float* __restrict__ bb,
    const float* __restrict__ m,  const float* __restrict__ v,
    const float* __restrict__ eW2, const float* __restrict__ eb2,
    const float* __restrict__ eW3, const float* __restrict__ eb3,
    float* __restrict__ e3out)
{
    int e    = blockIdx.x;
    int bt   = blockIdx.y;
    int tid  = threadIdx.x;
    int brow = bt * 16;

    __shared__ float fs[16][128];
    __shared__ float h1s[16][128];
    __shared__ float h2s[16][64];

#pragma unroll
    for (int i = 0; i < 16; ++i)
        fs[i][tid] = feats[(long)(brow + i) * 128 + tid];
    __syncthreads();

    {
        float acc[16];
        float bv = eb1[e * 128 + tid];
#pragma unroll
        for (int r = 0; r < 16; ++r) acc[r] = bv;
        const float* W = eW1 + (long)e * 128 * 128;
        for (int d = 0; d < 128; ++d) {
            float w = W[d * 128 + tid];
#pragma unroll
            for (int r = 0; r < 16; ++r) acc[r] += fs[r][d] * w;
        }
        float gg  = g[e * 128 + tid];
        float bbv = bb[e * 128 + tid];
        float mm  = m[e * 128 + tid];
        float inv = rsqrtf(v[e * 128 + tid] + EPS);
#pragma unroll
        for (int r = 0; r < 16; ++r) {
            float xx = fmaxf(acc[r], 0.f);
            h1s[r][tid] = (xx - mm) * inv * gg + bbv;
        }
    }
    __syncthreads();

    {
        int k = tid & 63, bg = tid >> 6;
        float acc[8];
        float bv = eb2[e * 64 + k];
#pragma unroll
        for (int r = 0; r < 8; ++r) acc[r] = bv;
        const float* W = eW2 + (long)e * 128 * 64;
        for (int d = 0; d < 128; ++d) {
            float w = W[d * 64 + k];
#pragma unroll
            for (int r = 0; r < 8; ++r) acc[r] += h1s[bg * 8 + r][d] * w;
        }
#pragma unroll
        for (int r = 0; r < 8; ++r) h2s[bg * 8 + r][k] = fmaxf(acc[r], 0.f);
    }
    __syncthreads();

    const float* W3 = eW3 + (long)e * 64 * 10;
    for (int t = tid; t < 160; t += 128) {
        int r = t / 10, c = t % 10;
        float acc = eb3[e * 10 + c];
#pragma unroll 8
        for (int k = 0; k < 64; ++k) acc += h2s[r][k] * W3[k * 10 + c];
        e3out[((long)e * 2048 + brow + r) * 10 + c] = acc;
    }
}

// ---------------------------------------------------------------------------
// Kernel 6: combine.
// ---------------------------------------------------------------------------
__global__ __launch_bounds__(256) void k_combine(
    const float* __restrict__ e3, const float* __restrict__ probs,
    float* __restrict__ out)
{
    int t = blockIdx.x * blockDim.x + threadIdx.x;
    if (t >= 2048 * 10) return;
    int b = t / 10, c = t % 10;
    float acc = 0.f;
#pragma unroll
    for (int e = 0; e < 16; ++e)
        acc += probs[(long)b * 16 + e] * e3[((long)e * 2048 + b) * 10 + c];
    out[t] = acc;
}

// ---------------------------------------------------------------------------
extern "C" void kernel_launch(void* const* d_in, const int* in_sizes, int n_in,
                              void* d_out, int out_size, void* d_ws, size_t ws_size,
                              hipStream_t stream)
{
    const float* x    = (const float*)d_in[0];
    const float* cW1  = (const float*)d_in[1];
    const float* cb1  = (const float*)d_in[2];
    const float* bn1g = (const float*)d_in[3];
    const float* bn1b = (const float*)d_in[4];
    const float* bn1m = (const float*)d_in[5];
    const float* bn1v = (const float*)d_in[6];
    const float* cW2  = (const float*)d_in[7];
    const float* cb2  = (const float*)d_in[8];
    const float* bn2g = (const float*)d_in[9];
    const float* bn2b = (const float*)d_in[10];
    const float* bn2m = (const float*)d_in[11];
    const float* bn2v = (const float*)d_in[12];
    const float* dW   = (const float*)d_in[13];
    const float* db   = (const float*)d_in[14];
    const float* rW1  = (const float*)d_in[15];
    const float* rb1  = (const float*)d_in[16];
    const float* rW2  = (const float*)d_in[17];
    const float* rb2  = (const float*)d_in[18];
    const float* eW1  = (const float*)d_in[19];
    const float* eb1  = (const float*)d_in[20];
    const float* ebng = (const float*)d_in[21];
    const float* ebnb = (const float*)d_in[22];
    const float* ebnm = (const float*)d_in[23];
    const float* ebnv = (const float*)d_in[24];
    const float* eW2  = (const float*)d_in[25];
    const float* eb2  = (const float*)d_in[26];
    const float* eW3  = (const float*)d_in[27];
    const float* eb3  = (const float*)d_in[28];

    float* ws    = (float*)d_ws;
    float* h1reg = ws;                     // 16,777,216 float slots
    _Float16* h1f = (_Float16*)h1reg;      // conv1 out f16 [2048*16*16*32]
    float* h2reg = h1reg + 16777216;       //  8,388,608 float slots
    _Float16* h2f = (_Float16*)h2reg;      // conv2 out f16 [2048][4096]
    _Float16* Wt2 = (_Float16*)(h2reg + 4194304);  // dense weights f16
    float* feats = h2reg + 8388608;        //    262,144
    float* probs = feats + 262144;         //     32,768
    float* e3    = probs + 32768;          //    327,680
    // Wt (conv2 w, 18432 f16) + Wt1 (conv1 w, 3072 f16) alias e3: both fully
    // consumed before k_expert writes e3; rewritten every launch.
    _Float16* Wt  = (_Float16*)e3;
    _Float16* Wt1 = Wt + 18432;
    float* out   = (float*)d_out;

    k_wprep1<<<24, 128, 0, stream>>>(cW1, Wt1);
    k_wprep<<<72, 256, 0, stream>>>(cW2, Wt);
    k_wprep2<<<64, 256, 0, stream>>>(dW, Wt2);
    k_conv1_mfma<<<2048, 256, 0, stream>>>(x, Wt1, cb1, bn1g, bn1b, bn1m, bn1v, h1f);
    k_conv2_mfma<<<2048, 256, 0, stream>>>(h1f, Wt, cb2, bn2g, bn2b, bn2m, bn2v, h2f);
    k_dense_mfma<<<128, 256, 0, stream>>>(h2f, Wt2, db, feats);
    k_router<<<2048, 64, 0, stream>>>(feats, rW1, rb1, rW2, rb2, probs);
    {
        dim3 grid(16, 128);
        k_expert<<<grid, 128, 0, stream>>>(feats, eW1, eb1, ebng, ebnb, ebnm, ebnv,
                                           eW2, eb2, eW3, eb3, e3);
    }
    k_combine<<<80, 256, 0, stream>>>(e3, probs, out);
}

// Round 6
// 133.550 us; speedup vs baseline: 8.0742x; 1.1459x over previous
//
#include <hip/hip_runtime.h>

#define EPS 1e-3f

typedef _Float16 half8 __attribute__((ext_vector_type(8)));
typedef _Float16 half4v __attribute__((ext_vector_type(4)));
typedef float f32x4 __attribute__((ext_vector_type(4)));

// ---------------------------------------------------------------------------
// Merged tiny weight preps:
//  region A: cW1 [3][3][3][32] -> Wt1 [3(ky)][32(co)][32(k)] f16 (k=kx*4+ci, zero pad)
//  region B: cW2 [3][3][32][64] -> Wt [9(tap)][64(co)][32(ci)] f16
//  region C: eW3 [16][64][10] -> eW3p [16][16(n, pad0)][64(k)] f16
// ---------------------------------------------------------------------------
__global__ __launch_bounds__(256) void k_wprep_small(
    const float* __restrict__ cW1, const float* __restrict__ cW2,
    const float* __restrict__ eW3,
    _Float16* __restrict__ Wt1, _Float16* __restrict__ Wt,
    _Float16* __restrict__ eW3p)
{
    int t = blockIdx.x * 256 + threadIdx.x;
    if (t < 3072) {
        int k = t & 31, co = (t >> 5) & 31, ky = t >> 10;
        int kx = k >> 2, ci = k & 3;
        float val = (kx < 3 && ci < 3) ? cW1[((ky * 3 + kx) * 3 + ci) * 32 + co] : 0.f;
        Wt1[t] = (_Float16)val;
    } else if (t < 3072 + 18432) {
        int u = t - 3072;
        int co = u & 63;
        int rest = u >> 6;
        int ci = rest & 31, tap = rest >> 5;
        Wt[(tap * 64 + co) * 32 + ci] = (_Float16)cW2[u];
    } else if (t < 3072 + 18432 + 16384) {
        int u = t - 21504;
        int k = u & 63, n = (u >> 6) & 15, e = u >> 10;
        float val = (n < 10) ? eW3[(e * 64 + k) * 10 + n] : 0.f;
        eW3p[(e * 16 + n) * 64 + k] = (_Float16)val;
    }
}

// ---------------------------------------------------------------------------
// Weight prep dense: dW fp32 [4096][128] -> Wt2 f16 [128][4096]
// ---------------------------------------------------------------------------
__global__ __launch_bounds__(256) void k_wprep2(
    const float* __restrict__ dW, _Float16* __restrict__ Wt2)
{
    __shared__ _Float16 lt[64][137];
    int kb  = blockIdx.x * 64;
    int tid = threadIdx.x;

    int c = tid & 127, r2 = tid >> 7;
#pragma unroll
    for (int it = 0; it < 32; ++it) {
        int r = it * 2 + r2;
        lt[r][c] = (_Float16)dW[(long)(kb + r) * 128 + c];
    }
    __syncthreads();

#pragma unroll
    for (int it = 0; it < 4; ++it) {
        int chunk = it * 256 + tid;
        int n = chunk >> 3, kc = (chunk & 7) * 8;
        half8 v;
#pragma unroll
        for (int j = 0; j < 8; ++j) v[j] = lt[kc + j][n];
        *(half8*)(Wt2 + (long)n * 4096 + kb + kc) = v;
    }
}

// ---------------------------------------------------------------------------
// Weight prep expert L1: eW1 [16][128(d)][128(h)] -> eW1t f16 [16][128(h)][128(d)]
// ---------------------------------------------------------------------------
__global__ __launch_bounds__(256) void k_wprep_e1(
    const float* __restrict__ eW1, _Float16* __restrict__ eW1t)
{
    __shared__ _Float16 lt[128][130];
    int e = blockIdx.x, tid = threadIdx.x;
    const float* src = eW1 + (long)e * 16384;
#pragma unroll
    for (int it = 0; it < 64; ++it) {
        int idx = it * 256 + tid;
        lt[idx >> 7][idx & 127] = (_Float16)src[idx];
    }
    __syncthreads();
    _Float16* dst = eW1t + (long)e * 16384;
#pragma unroll
    for (int it = 0; it < 64; ++it) {
        int idx = it * 256 + tid;           // idx = h*128 + d
        dst[idx] = lt[idx & 127][idx >> 7];
    }
}

// ---------------------------------------------------------------------------
// Weight prep expert L2: eW2 [16][128(h)][64(k)] -> eW2t f16 [16][64(k)][128(h)]
// ---------------------------------------------------------------------------
__global__ __launch_bounds__(256) void k_wprep_e2(
    const float* __restrict__ eW2, _Float16* __restrict__ eW2t)
{
    __shared__ _Float16 lt[128][66];
    int e = blockIdx.x, tid = threadIdx.x;
    const float* src = eW2 + (long)e * 8192;
#pragma unroll
    for (int it = 0; it < 32; ++it) {
        int idx = it * 256 + tid;
        lt[idx >> 6][idx & 63] = (_Float16)src[idx];
    }
    __syncthreads();
    _Float16* dst = eW2t + (long)e * 8192;
#pragma unroll
    for (int it = 0; it < 32; ++it) {
        int idx = it * 256 + tid;           // idx = n*128 + d
        dst[idx] = lt[idx & 127][idx >> 7];
    }
}

// ---------------------------------------------------------------------------
// Kernel 1: conv1 as implicit-GEMM f16 MFMA. One block per image.
// ---------------------------------------------------------------------------
__global__ __launch_bounds__(256) void k_conv1_mfma(
    const float* __restrict__ x, const _Float16* __restrict__ Wt1,
    const float* __restrict__ bias,
    const float* __restrict__ g, const float* __restrict__ bb,
    const float* __restrict__ m, const float* __restrict__ v,
    _Float16* __restrict__ out)
{
    __shared__ __align__(16) _Float16 As[34][40][4];
    int tid = threadIdx.x;
    int b = blockIdx.x;
    int w = tid >> 6, l = tid & 63;
    int l15 = l & 15, lq = l >> 4;

    {
        float4 z = make_float4(0.f, 0.f, 0.f, 0.f);
        float4* flat = (float4*)&As[0][0][0];
        for (int i = tid; i < 680; i += 256) flat[i] = z;
    }
    __syncthreads();

    {
        int y = tid >> 3, x0 = (tid & 7) * 4;
        const float* src = x + ((long)b * 1024 + y * 32 + x0) * 3;
        float4 f0 = *(const float4*)(src);
        float4 f1 = *(const float4*)(src + 4);
        float4 f2 = *(const float4*)(src + 8);
        half4v h0 = { (_Float16)f0.x, (_Float16)f0.y, (_Float16)f0.z, (_Float16)0.f };
        half4v h1 = { (_Float16)f0.w, (_Float16)f1.x, (_Float16)f1.y, (_Float16)0.f };
        half4v h2 = { (_Float16)f1.z, (_Float16)f1.w, (_Float16)f2.x, (_Float16)0.f };
        half4v h3 = { (_Float16)f2.y, (_Float16)f2.z, (_Float16)f2.w, (_Float16)0.f };
        *(half4v*)&As[y + 1][x0 + 1][0] = h0;
        *(half4v*)&As[y + 1][x0 + 2][0] = h1;
        *(half4v*)&As[y + 1][x0 + 3][0] = h2;
        *(half4v*)&As[y + 1][x0 + 4][0] = h3;
    }

    half8 bf[3][2];
#pragma unroll
    for (int ky = 0; ky < 3; ++ky)
#pragma unroll
        for (int nf = 0; nf < 2; ++nf)
            bf[ky][nf] = *(const half8*)(Wt1 + (ky * 32 + nf * 16 + l15) * 32 + lq * 8);

    float bv[2], gg[2], iv[2], mm[2], bbv[2];
#pragma unroll
    for (int nf = 0; nf < 2; ++nf) {
        int co = nf * 16 + l15;
        bv[nf] = bias[co]; gg[nf] = g[co]; bbv[nf] = bb[co]; mm[nf] = m[co];
        iv[nf] = rsqrtf(v[co] + EPS);
    }
    __syncthreads();

    int y0 = w * 8;
#pragma unroll
    for (int pr = 0; pr < 4; ++pr) {
        int ya = y0 + 2 * pr;
        f32x4 acc[2][2][2];
#pragma unroll
        for (int r = 0; r < 2; ++r)
#pragma unroll
            for (int h = 0; h < 2; ++h)
#pragma unroll
                for (int nf = 0; nf < 2; ++nf)
                    acc[r][h][nf] = (f32x4){ bv[nf], bv[nf], bv[nf], bv[nf] };

#pragma unroll
        for (int ky = 0; ky < 3; ++ky)
#pragma unroll
            for (int r = 0; r < 2; ++r)
#pragma unroll
                for (int h = 0; h < 2; ++h) {
                    const _Float16* ap = &As[ya + r + ky][h * 16 + l15 + 2 * lq][0];
                    half4v a0 = *(const half4v*)ap;
                    half4v a1 = *(const half4v*)(ap + 4);
                    half8 af = __builtin_shufflevector(a0, a1, 0, 1, 2, 3, 4, 5, 6, 7);
#pragma unroll
                    for (int nf = 0; nf < 2; ++nf)
                        acc[r][h][nf] = __builtin_amdgcn_mfma_f32_16x16x32_f16(
                            af, bf[ky][nf], acc[r][h][nf], 0, 0, 0);
                }

        int py = w * 4 + pr;
#pragma unroll
        for (int h = 0; h < 2; ++h)
#pragma unroll
            for (int nf = 0; nf < 2; ++nf) {
                f32x4 aA = acc[0][h][nf], aB = acc[1][h][nf];
                float p0 = fmaxf(fmaxf(aA[0], aA[1]), fmaxf(aB[0], aB[1]));
                float p1 = fmaxf(fmaxf(aA[2], aA[3]), fmaxf(aB[2], aB[3]));
                p0 = fmaxf(p0, 0.f); p1 = fmaxf(p1, 0.f);
                p0 = (p0 - mm[nf]) * iv[nf] * gg[nf] + bbv[nf];
                p1 = (p1 - mm[nf]) * iv[nf] * gg[nf] + bbv[nf];
                int px = h * 8 + lq * 2;
                int co = nf * 16 + l15;
                long base = (((long)b * 16 + py) * 16 + px) * 32 + co;
                out[base]      = (_Float16)p0;
                out[base + 32] = (_Float16)p1;
            }
    }
}

// ---------------------------------------------------------------------------
// Kernel 2: conv2 as implicit-GEMM f16 MFMA -> h2 f16 [2048][4096]
// ---------------------------------------------------------------------------
__global__ __launch_bounds__(256) void k_conv2_mfma(
    const _Float16* __restrict__ h1f, const _Float16* __restrict__ Wt,
    const float* __restrict__ bias,
    const float* __restrict__ g, const float* __restrict__ bb,
    const float* __restrict__ m, const float* __restrict__ v,
    _Float16* __restrict__ out)
{
    __shared__ __align__(16) _Float16 As[18][18][40];
    int tid = threadIdx.x;
    int b   = blockIdx.x;
    int w   = tid >> 6;
    int l   = tid & 63;
    int l15 = l & 15, lq = l >> 4;

    {
        _Float16* flat = &As[0][0][0];
        for (int i = tid * 8; i < 18 * 18 * 40; i += 256 * 8)
            *(float4*)(flat + i) = make_float4(0.f, 0.f, 0.f, 0.f);
    }
    __syncthreads();

    {
        const _Float16* src = h1f + ((long)b * 256 + tid) * 32;
        _Float16* dst = &As[(tid >> 4) + 1][(tid & 15) + 1][0];
#pragma unroll
        for (int i = 0; i < 4; ++i)
            *(half8*)(dst + i * 8) = *(const half8*)(src + i * 8);
    }

    f32x4 acc[4][4];
#pragma unroll
    for (int nf = 0; nf < 4; ++nf) {
        float bv = bias[nf * 16 + l15];
#pragma unroll
        for (int mf = 0; mf < 4; ++mf)
            acc[mf][nf] = (f32x4){ bv, bv, bv, bv };
    }
    __syncthreads();

    int row0 = 4 * w;
#pragma unroll
    for (int tap = 0; tap < 9; ++tap) {
        int ky = tap / 3, kx = tap % 3;
        half8 bf[4];
        const _Float16* wb = Wt + ((long)(tap * 64 + l15)) * 32 + lq * 8;
#pragma unroll
        for (int nf = 0; nf < 4; ++nf)
            bf[nf] = *(const half8*)(wb + (long)nf * 16 * 32);
#pragma unroll
        for (int mf = 0; mf < 4; ++mf) {
            const _Float16* ap = &As[row0 + mf + ky][l15 + kx][lq * 8];
            half8 af = *(const half8*)ap;
#pragma unroll
            for (int nf = 0; nf < 4; ++nf)
                acc[mf][nf] = __builtin_amdgcn_mfma_f32_16x16x32_f16(
                    af, bf[nf], acc[mf][nf], 0, 0, 0);
        }
    }

#pragma unroll
    for (int nf = 0; nf < 4; ++nf) {
        int co = nf * 16 + l15;
        float gg = g[co], bbv = bb[co], mm = m[co];
        float iv = rsqrtf(v[co] + EPS);
#pragma unroll
        for (int pr = 0; pr < 2; ++pr) {
            int prow = 2 * w + pr;
            f32x4 a0 = acc[2 * pr][nf];
            f32x4 a1 = acc[2 * pr + 1][nf];
            float p0 = fmaxf(fmaxf(a0[0], a0[1]), fmaxf(a1[0], a1[1]));
            float p1 = fmaxf(fmaxf(a0[2], a0[3]), fmaxf(a1[2], a1[3]));
            p0 = fmaxf(p0, 0.f);
            p1 = fmaxf(p1, 0.f);
            int ppx = lq * 2;
            long base = (((long)b * 8 + prow) * 8) * 64 + co;
            out[base + (long)(ppx    ) * 64] = (_Float16)((p0 - mm) * iv * gg + bbv);
            out[base + (long)(ppx + 1) * 64] = (_Float16)((p1 - mm) * iv * gg + bbv);
        }
    }
}

// ---------------------------------------------------------------------------
// Kernel 3: dense 4096 -> 128 + relu as f16 MFMA; emits fp32 + f16 feats.
// ---------------------------------------------------------------------------
__global__ __launch_bounds__(256) void k_dense_mfma(
    const _Float16* __restrict__ h2f, const _Float16* __restrict__ Wt2,
    const float* __restrict__ db, float* __restrict__ feats,
    _Float16* __restrict__ featsH)
{
    __shared__ __align__(16) _Float16 As[16][264];
    int tid = threadIdx.x;
    int w = tid >> 6, l = tid & 63;
    int l15 = l & 15, lq = l >> 4;
    int brow = blockIdx.x * 16;
    int n0 = w * 32;

    f32x4 acc[2];
#pragma unroll
    for (int nf = 0; nf < 2; ++nf) {
        float bv = db[n0 + nf * 16 + l15];
        acc[nf] = (f32x4){ bv, bv, bv, bv };
    }

    int srow = tid >> 4, sc = (tid & 15) * 16;
    for (int k0 = 0; k0 < 4096; k0 += 256) {
        __syncthreads();
        const _Float16* src = h2f + (long)(brow + srow) * 4096 + k0 + sc;
        half8 v0 = *(const half8*)src;
        half8 v1 = *(const half8*)(src + 8);
        *(half8*)(&As[srow][sc])     = v0;
        *(half8*)(&As[srow][sc + 8]) = v1;
        __syncthreads();
#pragma unroll
        for (int kk = 0; kk < 256; kk += 32) {
            half8 af = *(const half8*)(&As[l15][kk + lq * 8]);
#pragma unroll
            for (int nf = 0; nf < 2; ++nf) {
                half8 bf = *(const half8*)(Wt2 + (long)(n0 + nf * 16 + l15) * 4096
                                           + k0 + kk + lq * 8);
                acc[nf] = __builtin_amdgcn_mfma_f32_16x16x32_f16(af, bf, acc[nf], 0, 0, 0);
            }
        }
    }

#pragma unroll
    for (int nf = 0; nf < 2; ++nf) {
        int n = n0 + nf * 16 + l15;
#pragma unroll
        for (int reg = 0; reg < 4; ++reg) {
            int b = brow + lq * 4 + reg;
            float val = fmaxf(acc[nf][reg], 0.f);
            feats[(long)b * 128 + n] = val;
            featsH[(long)b * 128 + n] = (_Float16)val;
        }
    }
}

// ---------------------------------------------------------------------------
// Kernel 4: router MLP + softmax.
// ---------------------------------------------------------------------------
__global__ __launch_bounds__(64) void k_router(
    const float* __restrict__ feats,
    const float* __restrict__ rW1, const float* __restrict__ rb1,
    const float* __restrict__ rW2, const float* __restrict__ rb2,
    float* __restrict__ probs)
{
    __shared__ float f[128];
    __shared__ float r1[64];
    __shared__ float lg[16];
    int b = blockIdx.x, tid = threadIdx.x;

    f[tid]      = feats[(long)b * 128 + tid];
    f[tid + 64] = feats[(long)b * 128 + 64 + tid];
    __syncthreads();

    float acc = rb1[tid];
#pragma unroll 8
    for (int d = 0; d < 128; ++d) acc += f[d] * rW1[d * 64 + tid];
    r1[tid] = fmaxf(acc, 0.f);
    __syncthreads();

    if (tid < 16) {
        float a = rb2[tid];
#pragma unroll 8
        for (int k = 0; k < 64; ++k) a += r1[k] * rW2[k * 16 + tid];
        lg[tid] = a;
    }
    __syncthreads();

    if (tid == 0) {
        float mx = lg[0];
#pragma unroll
        for (int i = 1; i < 16; ++i) mx = fmaxf(mx, lg[i]);
        float s = 0.f, e[16];
#pragma unroll
        for (int i = 0; i < 16; ++i) { e[i] = __expf(lg[i] - mx); s += e[i]; }
        float inv = 1.f / s;
#pragma unroll
        for (int i = 0; i < 16; ++i) probs[(long)b * 16 + i] = e[i] * inv;
    }
}

// ---------------------------------------------------------------------------
// Kernel 5: fused expert chain, f16 MFMA.
// Grid (16 experts, 32 b-tiles of 64). 4 waves x 16 rows each.
// e3p output: [16][2048][16] fp32 (cols 10..15 exactly 0).
// ---------------------------------------------------------------------------
__global__ __launch_bounds__(256) void k_expert_mfma(
    const _Float16* __restrict__ featsH,
    const _Float16* __restrict__ eW1t, const float* __restrict__ eb1,
    const float* __restrict__ g,  const float* __restrict__ bb,
    const float* __restrict__ m,  const float* __restrict__ v,
    const _Float16* __restrict__ eW2t, const float* __restrict__ eb2,
    const _Float16* __restrict__ eW3p, const float* __restrict__ eb3,
    float* __restrict__ e3p)
{
    __shared__ __align__(16) _Float16 fsH[64][136];
    __shared__ __align__(16) _Float16 h1sH[64][136];
    __shared__ __align__(16) _Float16 h2sH[64][72];
    int e = blockIdx.x, bt = blockIdx.y;
    int tid = threadIdx.x;
    int w = tid >> 6, l = tid & 63, l15 = l & 15, lq = l >> 4;
    int brow = bt * 64, m0 = w * 16;

#pragma unroll
    for (int it = 0; it < 4; ++it) {
        int idx = it * 256 + tid;
        int r = idx >> 4, c = (idx & 15) * 8;
        *(half8*)&fsH[r][c] = *(const half8*)(featsH + (long)(brow + r) * 128 + c);
    }
    __syncthreads();

    // phase 1: [64x128] @ [128x128] + BN + relu
    {
        half8 af[4];
#pragma unroll
        for (int kq = 0; kq < 4; ++kq)
            af[kq] = *(const half8*)&fsH[m0 + l15][kq * 32 + lq * 8];
        const _Float16* B1 = eW1t + (long)e * 16384 + l15 * 128 + lq * 8;
        f32x4 acc[8];
#pragma unroll
        for (int nf = 0; nf < 8; ++nf) {
            float bv = eb1[e * 128 + nf * 16 + l15];
            acc[nf] = (f32x4){ bv, bv, bv, bv };
        }
#pragma unroll
        for (int nf = 0; nf < 8; ++nf)
#pragma unroll
            for (int kq = 0; kq < 4; ++kq) {
                half8 bfv = *(const half8*)(B1 + nf * 2048 + kq * 32);
                acc[nf] = __builtin_amdgcn_mfma_f32_16x16x32_f16(af[kq], bfv, acc[nf], 0, 0, 0);
            }
#pragma unroll
        for (int nf = 0; nf < 8; ++nf) {
            int h = nf * 16 + l15;
            float gg = g[e * 128 + h], bbv = bb[e * 128 + h], mm = m[e * 128 + h];
            float iv = rsqrtf(v[e * 128 + h] + EPS);
#pragma unroll
            for (int reg = 0; reg < 4; ++reg) {
                float val = fmaxf(acc[nf][reg], 0.f);
                h1sH[m0 + lq * 4 + reg][h] = (_Float16)((val - mm) * iv * gg + bbv);
            }
        }
    }
    __syncthreads();

    // phase 2: [64x128] @ [128x64] + relu
    {
        half8 af[4];
#pragma unroll
        for (int kq = 0; kq < 4; ++kq)
            af[kq] = *(const half8*)&h1sH[m0 + l15][kq * 32 + lq * 8];
        const _Float16* B2 = eW2t + (long)e * 8192 + l15 * 128 + lq * 8;
        f32x4 acc[4];
#pragma unroll
        for (int nf = 0; nf < 4; ++nf) {
            float bv = eb2[e * 64 + nf * 16 + l15];
            acc[nf] = (f32x4){ bv, bv, bv, bv };
        }
#pragma unroll
        for (int nf = 0; nf < 4; ++nf)
#pragma unroll
            for (int kq = 0; kq < 4; ++kq) {
                half8 bfv = *(const half8*)(B2 + nf * 2048 + kq * 32);
                acc[nf] = __builtin_amdgcn_mfma_f32_16x16x32_f16(af[kq], bfv, acc[nf], 0, 0, 0);
            }
#pragma unroll
        for (int nf = 0; nf < 4; ++nf)
#pragma unroll
            for (int reg = 0; reg < 4; ++reg)
                h2sH[m0 + lq * 4 + reg][nf * 16 + l15] = (_Float16)fmaxf(acc[nf][reg], 0.f);
    }
    __syncthreads();

    // phase 3: [64x64] @ [64x16(pad)] -> e3p
    {
        half8 af[2];
#pragma unroll
        for (int kq = 0; kq < 2; ++kq)
            af[kq] = *(const half8*)&h2sH[m0 + l15][kq * 32 + lq * 8];
        const _Float16* B3 = eW3p + (long)e * 1024 + l15 * 64 + lq * 8;
        float bv = (l15 < 10) ? eb3[e * 10 + l15] : 0.f;
        f32x4 acc = (f32x4){ bv, bv, bv, bv };
#pragma unroll
        for (int kq = 0; kq < 2; ++kq) {
            half8 bfv = *(const half8*)(B3 + kq * 32);
            acc = __builtin_amdgcn_mfma_f32_16x16x32_f16(af[kq], bfv, acc, 0, 0, 0);
        }
#pragma unroll
        for (int reg = 0; reg < 4; ++reg) {
            int b = brow + m0 + lq * 4 + reg;
            e3p[((long)e * 2048 + b) * 16 + l15] = acc[reg];
        }
    }
}

// ---------------------------------------------------------------------------
// Kernel 6: combine.  out[b][c] = sum_e probs[b][e] * e3p[e][b][c]
// ---------------------------------------------------------------------------
__global__ __launch_bounds__(256) void k_combine(
    const float* __restrict__ e3p, const float* __restrict__ probs,
    float* __restrict__ out)
{
    int t = blockIdx.x * blockDim.x + threadIdx.x;
    if (t >= 2048 * 10) return;
    int b = t / 10, c = t % 10;
    float acc = 0.f;
#pragma unroll
    for (int e = 0; e < 16; ++e)
        acc += probs[(long)b * 16 + e] * e3p[((long)e * 2048 + b) * 16 + c];
    out[t] = acc;
}

// ---------------------------------------------------------------------------
extern "C" void kernel_launch(void* const* d_in, const int* in_sizes, int n_in,
                              void* d_out, int out_size, void* d_ws, size_t ws_size,
                              hipStream_t stream)
{
    const float* x    = (const float*)d_in[0];
    const float* cW1  = (const float*)d_in[1];
    const float* cb1  = (const float*)d_in[2];
    const float* bn1g = (const float*)d_in[3];
    const float* bn1b = (const float*)d_in[4];
    const float* bn1m = (const float*)d_in[5];
    const float* bn1v = (const float*)d_in[6];
    const float* cW2  = (const float*)d_in[7];
    const float* cb2  = (const float*)d_in[8];
    const float* bn2g = (const float*)d_in[9];
    const float* bn2b = (const float*)d_in[10];
    const float* bn2m = (const float*)d_in[11];
    const float* bn2v = (const float*)d_in[12];
    const float* dW   = (const float*)d_in[13];
    const float* db   = (const float*)d_in[14];
    const float* rW1  = (const float*)d_in[15];
    const float* rb1  = (const float*)d_in[16];
    const float* rW2  = (const float*)d_in[17];
    const float* rb2  = (const float*)d_in[18];
    const float* eW1  = (const float*)d_in[19];
    const float* eb1  = (const float*)d_in[20];
    const float* ebng = (const float*)d_in[21];
    const float* ebnb = (const float*)d_in[22];
    const float* ebnm = (const float*)d_in[23];
    const float* ebnv = (const float*)d_in[24];
    const float* eW2  = (const float*)d_in[25];
    const float* eb2  = (const float*)d_in[26];
    const float* eW3  = (const float*)d_in[27];
    const float* eb3  = (const float*)d_in[28];

    float* ws    = (float*)d_ws;
    // --- region 1: h1reg (16,777,216 float slots) ---
    float* h1reg = ws;
    _Float16* h1f = (_Float16*)h1reg;      // conv1 out f16, 16.7M f16 = first 8,388,608 floats
    // After conv2 consumes h1f, this region is recycled:
    float* e3p   = h1reg;                                  // [0 .. 524,288) floats
    _Float16* featsH = (_Float16*)(h1reg + 524288);        // 262,144 f16 = [524,288 .. 655,360) floats
    // --- region 2: h2reg (8,388,608 float slots) ---
    float* h2reg = h1reg + 16777216;
    _Float16* h2f = (_Float16*)h2reg;                      // conv2 out f16 [2048][4096]
    _Float16* Wt2 = (_Float16*)(h2reg + 4194304);          // dense weights f16 [128][4096]
    // --- region 3: small tensors ---
    float* feats = h2reg + 8388608;        //    262,144 floats
    float* probs = feats + 262144;         //     32,768 floats
    float* ewreg = probs + 32768;
    _Float16* eW1t = (_Float16*)ewreg;             // 262,144 f16
    _Float16* eW2t = eW1t + 262144;                // 131,072 f16
    _Float16* eW3p = eW2t + 131072;                //  16,384 f16
    _Float16* Wt   = eW3p + 16384;                 //  18,432 f16 (conv2 w)
    _Float16* Wt1  = Wt + 18432;                   //   3,072 f16 (conv1 w)
    float* out   = (float*)d_out;

    k_wprep_small<<<148, 256, 0, stream>>>(cW1, cW2, eW3, Wt1, Wt, eW3p);
    k_wprep2<<<64, 256, 0, stream>>>(dW, Wt2);
    k_wprep_e1<<<16, 256, 0, stream>>>(eW1, eW1t);
    k_wprep_e2<<<16, 256, 0, stream>>>(eW2, eW2t);
    k_conv1_mfma<<<2048, 256, 0, stream>>>(x, Wt1, cb1, bn1g, bn1b, bn1m, bn1v, h1f);
    k_conv2_mfma<<<2048, 256, 0, stream>>>(h1f, Wt, cb2, bn2g, bn2b, bn2m, bn2v, h2f);
    k_dense_mfma<<<128, 256, 0, stream>>>(h2f, Wt2, db, feats, featsH);
    k_router<<<2048, 64, 0, stream>>>(feats, rW1, rb1, rW2, rb2, probs);
    {
        dim3 grid(16, 32);
        k_expert_mfma<<<grid, 256, 0, stream>>>(featsH, eW1t, eb1, ebng, ebnb, ebnm, ebnv,
                                                eW2t, eb2, eW3p, eb3, e3p);
    }
    k_combine<<<80, 256, 0, stream>>>(e3p, probs, out);
}

// Round 7
// 116.750 us; speedup vs baseline: 9.2360x; 1.1439x over previous
//
#include <hip/hip_runtime.h>

#define EPS 1e-3f

typedef _Float16 half8 __attribute__((ext_vector_type(8)));
typedef _Float16 half4v __attribute__((ext_vector_type(4)));
typedef float f32x4 __attribute__((ext_vector_type(4)));

// ---------------------------------------------------------------------------
// Merged tiny weight preps:
//  region A: cW1 [3][3][3][32] -> Wt1 [3(ky)][32(co)][32(k)] f16 (k=kx*4+ci, zero pad)
//  region B: cW2 [3][3][32][64] -> Wt [9(tap)][64(co)][32(ci)] f16
//  region C: eW3 [16][64][10] -> eW3p [16][16(n, pad0)][64(k)] f16
// ---------------------------------------------------------------------------
__global__ __launch_bounds__(256) void k_wprep_small(
    const float* __restrict__ cW1, const float* __restrict__ cW2,
    const float* __restrict__ eW3,
    _Float16* __restrict__ Wt1, _Float16* __restrict__ Wt,
    _Float16* __restrict__ eW3p)
{
    int t = blockIdx.x * 256 + threadIdx.x;
    if (t < 3072) {
        int k = t & 31, co = (t >> 5) & 31, ky = t >> 10;
        int kx = k >> 2, ci = k & 3;
        float val = (kx < 3 && ci < 3) ? cW1[((ky * 3 + kx) * 3 + ci) * 32 + co] : 0.f;
        Wt1[t] = (_Float16)val;
    } else if (t < 3072 + 18432) {
        int u = t - 3072;
        int co = u & 63;
        int rest = u >> 6;
        int ci = rest & 31, tap = rest >> 5;
        Wt[(tap * 64 + co) * 32 + ci] = (_Float16)cW2[u];
    } else if (t < 3072 + 18432 + 16384) {
        int u = t - 21504;
        int k = u & 63, n = (u >> 6) & 15, e = u >> 10;
        float val = (n < 10) ? eW3[(e * 64 + k) * 10 + n] : 0.f;
        eW3p[(e * 16 + n) * 64 + k] = (_Float16)val;
    }
}

// ---------------------------------------------------------------------------
// Weight prep dense: dW fp32 [4096][128] -> Wt2 f16 [128][4096]
// ---------------------------------------------------------------------------
__global__ __launch_bounds__(256) void k_wprep2(
    const float* __restrict__ dW, _Float16* __restrict__ Wt2)
{
    __shared__ _Float16 lt[64][137];
    int kb  = blockIdx.x * 64;
    int tid = threadIdx.x;

    int c = tid & 127, r2 = tid >> 7;
#pragma unroll
    for (int it = 0; it < 32; ++it) {
        int r = it * 2 + r2;
        lt[r][c] = (_Float16)dW[(long)(kb + r) * 128 + c];
    }
    __syncthreads();

#pragma unroll
    for (int it = 0; it < 4; ++it) {
        int chunk = it * 256 + tid;
        int n = chunk >> 3, kc = (chunk & 7) * 8;
        half8 v;
#pragma unroll
        for (int j = 0; j < 8; ++j) v[j] = lt[kc + j][n];
        *(half8*)(Wt2 + (long)n * 4096 + kb + kc) = v;
    }
}

// ---------------------------------------------------------------------------
// Weight prep expert L1: eW1 [16][128(d)][128(h)] -> eW1t f16 [16][128(h)][128(d)]
// ---------------------------------------------------------------------------
__global__ __launch_bounds__(256) void k_wprep_e1(
    const float* __restrict__ eW1, _Float16* __restrict__ eW1t)
{
    __shared__ _Float16 lt[128][130];
    int e = blockIdx.x, tid = threadIdx.x;
    const float* src = eW1 + (long)e * 16384;
#pragma unroll
    for (int it = 0; it < 64; ++it) {
        int idx = it * 256 + tid;
        lt[idx >> 7][idx & 127] = (_Float16)src[idx];
    }
    __syncthreads();
    _Float16* dst = eW1t + (long)e * 16384;
#pragma unroll
    for (int it = 0; it < 64; ++it) {
        int idx = it * 256 + tid;           // idx = h*128 + d
        dst[idx] = lt[idx & 127][idx >> 7];
    }
}

// ---------------------------------------------------------------------------
// Weight prep expert L2: eW2 [16][128(h)][64(k)] -> eW2t f16 [16][64(k)][128(h)]
// ---------------------------------------------------------------------------
__global__ __launch_bounds__(256) void k_wprep_e2(
    const float* __restrict__ eW2, _Float16* __restrict__ eW2t)
{
    __shared__ _Float16 lt[128][66];
    int e = blockIdx.x, tid = threadIdx.x;
    const float* src = eW2 + (long)e * 8192;
#pragma unroll
    for (int it = 0; it < 32; ++it) {
        int idx = it * 256 + tid;
        lt[idx >> 6][idx & 63] = (_Float16)src[idx];
    }
    __syncthreads();
    _Float16* dst = eW2t + (long)e * 8192;
#pragma unroll
    for (int it = 0; it < 32; ++it) {
        int idx = it * 256 + tid;           // idx = n*128 + d
        dst[idx] = lt[idx & 127][idx >> 7];
    }
}

// ---------------------------------------------------------------------------
// Kernel 1: conv1 as implicit-GEMM f16 MFMA. One block per image.
// ---------------------------------------------------------------------------
__global__ __launch_bounds__(256) void k_conv1_mfma(
    const float* __restrict__ x, const _Float16* __restrict__ Wt1,
    const float* __restrict__ bias,
    const float* __restrict__ g, const float* __restrict__ bb,
    const float* __restrict__ m, const float* __restrict__ v,
    _Float16* __restrict__ out)
{
    __shared__ __align__(16) _Float16 As[34][40][4];
    int tid = threadIdx.x;
    int b = blockIdx.x;
    int w = tid >> 6, l = tid & 63;
    int l15 = l & 15, lq = l >> 4;

    {
        float4 z = make_float4(0.f, 0.f, 0.f, 0.f);
        float4* flat = (float4*)&As[0][0][0];
        for (int i = tid; i < 680; i += 256) flat[i] = z;
    }
    __syncthreads();

    {
        int y = tid >> 3, x0 = (tid & 7) * 4;
        const float* src = x + ((long)b * 1024 + y * 32 + x0) * 3;
        float4 f0 = *(const float4*)(src);
        float4 f1 = *(const float4*)(src + 4);
        float4 f2 = *(const float4*)(src + 8);
        half4v h0 = { (_Float16)f0.x, (_Float16)f0.y, (_Float16)f0.z, (_Float16)0.f };
        half4v h1 = { (_Float16)f0.w, (_Float16)f1.x, (_Float16)f1.y, (_Float16)0.f };
        half4v h2 = { (_Float16)f1.z, (_Float16)f1.w, (_Float16)f2.x, (_Float16)0.f };
        half4v h3 = { (_Float16)f2.y, (_Float16)f2.z, (_Float16)f2.w, (_Float16)0.f };
        *(half4v*)&As[y + 1][x0 + 1][0] = h0;
        *(half4v*)&As[y + 1][x0 + 2][0] = h1;
        *(half4v*)&As[y + 1][x0 + 3][0] = h2;
        *(half4v*)&As[y + 1][x0 + 4][0] = h3;
    }

    half8 bf[3][2];
#pragma unroll
    for (int ky = 0; ky < 3; ++ky)
#pragma unroll
        for (int nf = 0; nf < 2; ++nf)
            bf[ky][nf] = *(const half8*)(Wt1 + (ky * 32 + nf * 16 + l15) * 32 + lq * 8);

    float bv[2], gg[2], iv[2], mm[2], bbv[2];
#pragma unroll
    for (int nf = 0; nf < 2; ++nf) {
        int co = nf * 16 + l15;
        bv[nf] = bias[co]; gg[nf] = g[co]; bbv[nf] = bb[co]; mm[nf] = m[co];
        iv[nf] = rsqrtf(v[co] + EPS);
    }
    __syncthreads();

    int y0 = w * 8;
#pragma unroll
    for (int pr = 0; pr < 4; ++pr) {
        int ya = y0 + 2 * pr;
        f32x4 acc[2][2][2];
#pragma unroll
        for (int r = 0; r < 2; ++r)
#pragma unroll
            for (int h = 0; h < 2; ++h)
#pragma unroll
                for (int nf = 0; nf < 2; ++nf)
                    acc[r][h][nf] = (f32x4){ bv[nf], bv[nf], bv[nf], bv[nf] };

#pragma unroll
        for (int ky = 0; ky < 3; ++ky)
#pragma unroll
            for (int r = 0; r < 2; ++r)
#pragma unroll
                for (int h = 0; h < 2; ++h) {
                    const _Float16* ap = &As[ya + r + ky][h * 16 + l15 + 2 * lq][0];
                    half4v a0 = *(const half4v*)ap;
                    half4v a1 = *(const half4v*)(ap + 4);
                    half8 af = __builtin_shufflevector(a0, a1, 0, 1, 2, 3, 4, 5, 6, 7);
#pragma unroll
                    for (int nf = 0; nf < 2; ++nf)
                        acc[r][h][nf] = __builtin_amdgcn_mfma_f32_16x16x32_f16(
                            af, bf[ky][nf], acc[r][h][nf], 0, 0, 0);
                }

        int py = w * 4 + pr;
#pragma unroll
        for (int h = 0; h < 2; ++h)
#pragma unroll
            for (int nf = 0; nf < 2; ++nf) {
                f32x4 aA = acc[0][h][nf], aB = acc[1][h][nf];
                float p0 = fmaxf(fmaxf(aA[0], aA[1]), fmaxf(aB[0], aB[1]));
                float p1 = fmaxf(fmaxf(aA[2], aA[3]), fmaxf(aB[2], aB[3]));
                p0 = fmaxf(p0, 0.f); p1 = fmaxf(p1, 0.f);
                p0 = (p0 - mm[nf]) * iv[nf] * gg[nf] + bbv[nf];
                p1 = (p1 - mm[nf]) * iv[nf] * gg[nf] + bbv[nf];
                int px = h * 8 + lq * 2;
                int co = nf * 16 + l15;
                long base = (((long)b * 16 + py) * 16 + px) * 32 + co;
                out[base]      = (_Float16)p0;
                out[base + 32] = (_Float16)p1;
            }
    }
}

// ---------------------------------------------------------------------------
// Kernel 2: conv2 as implicit-GEMM f16 MFMA -> h2 f16 [2048][4096]
// ---------------------------------------------------------------------------
__global__ __launch_bounds__(256) void k_conv2_mfma(
    const _Float16* __restrict__ h1f, const _Float16* __restrict__ Wt,
    const float* __restrict__ bias,
    const float* __restrict__ g, const float* __restrict__ bb,
    const float* __restrict__ m, const float* __restrict__ v,
    _Float16* __restrict__ out)
{
    __shared__ __align__(16) _Float16 As[18][18][40];
    int tid = threadIdx.x;
    int b   = blockIdx.x;
    int w   = tid >> 6;
    int l   = tid & 63;
    int l15 = l & 15, lq = l >> 4;

    {
        _Float16* flat = &As[0][0][0];
        for (int i = tid * 8; i < 18 * 18 * 40; i += 256 * 8)
            *(float4*)(flat + i) = make_float4(0.f, 0.f, 0.f, 0.f);
    }
    __syncthreads();

    {
        const _Float16* src = h1f + ((long)b * 256 + tid) * 32;
        _Float16* dst = &As[(tid >> 4) + 1][(tid & 15) + 1][0];
#pragma unroll
        for (int i = 0; i < 4; ++i)
            *(half8*)(dst + i * 8) = *(const half8*)(src + i * 8);
    }

    f32x4 acc[4][4];
#pragma unroll
    for (int nf = 0; nf < 4; ++nf) {
        float bv = bias[nf * 16 + l15];
#pragma unroll
        for (int mf = 0; mf < 4; ++mf)
            acc[mf][nf] = (f32x4){ bv, bv, bv, bv };
    }
    __syncthreads();

    int row0 = 4 * w;
#pragma unroll
    for (int tap = 0; tap < 9; ++tap) {
        int ky = tap / 3, kx = tap % 3;
        half8 bf[4];
        const _Float16* wb = Wt + ((long)(tap * 64 + l15)) * 32 + lq * 8;
#pragma unroll
        for (int nf = 0; nf < 4; ++nf)
            bf[nf] = *(const half8*)(wb + (long)nf * 16 * 32);
#pragma unroll
        for (int mf = 0; mf < 4; ++mf) {
            const _Float16* ap = &As[row0 + mf + ky][l15 + kx][lq * 8];
            half8 af = *(const half8*)ap;
#pragma unroll
            for (int nf = 0; nf < 4; ++nf)
                acc[mf][nf] = __builtin_amdgcn_mfma_f32_16x16x32_f16(
                    af, bf[nf], acc[mf][nf], 0, 0, 0);
        }
    }

#pragma unroll
    for (int nf = 0; nf < 4; ++nf) {
        int co = nf * 16 + l15;
        float gg = g[co], bbv = bb[co], mm = m[co];
        float iv = rsqrtf(v[co] + EPS);
#pragma unroll
        for (int pr = 0; pr < 2; ++pr) {
            int prow = 2 * w + pr;
            f32x4 a0 = acc[2 * pr][nf];
            f32x4 a1 = acc[2 * pr + 1][nf];
            float p0 = fmaxf(fmaxf(a0[0], a0[1]), fmaxf(a1[0], a1[1]));
            float p1 = fmaxf(fmaxf(a0[2], a0[3]), fmaxf(a1[2], a1[3]));
            p0 = fmaxf(p0, 0.f);
            p1 = fmaxf(p1, 0.f);
            int ppx = lq * 2;
            long base = (((long)b * 8 + prow) * 8) * 64 + co;
            out[base + (long)(ppx    ) * 64] = (_Float16)((p0 - mm) * iv * gg + bbv);
            out[base + (long)(ppx + 1) * 64] = (_Float16)((p1 - mm) * iv * gg + bbv);
        }
    }
}

// ---------------------------------------------------------------------------
// Kernel 3a: dense 4096 -> 128, split-K x8, f16 MFMA. No bias (added in reduce).
// Grid (128 m-tiles, 8 k-chunks of 512). Partial out: pws[kc][2048][128] fp32.
// ---------------------------------------------------------------------------
__global__ __launch_bounds__(256) void k_dense_mfma(
    const _Float16* __restrict__ h2f, const _Float16* __restrict__ Wt2,
    float* __restrict__ pws)
{
    __shared__ __align__(16) _Float16 As[16][264];
    int tid = threadIdx.x;
    int w = tid >> 6, l = tid & 63;
    int l15 = l & 15, lq = l >> 4;
    int brow = blockIdx.x * 16;
    int kbase = blockIdx.y * 512;
    int n0 = w * 32;

    f32x4 acc[2] = { (f32x4){0.f,0.f,0.f,0.f}, (f32x4){0.f,0.f,0.f,0.f} };

    int srow = tid >> 4, sc = (tid & 15) * 16;
#pragma unroll
    for (int k0 = 0; k0 < 512; k0 += 256) {
        __syncthreads();
        const _Float16* src = h2f + (long)(brow + srow) * 4096 + kbase + k0 + sc;
        half8 v0 = *(const half8*)src;
        half8 v1 = *(const half8*)(src + 8);
        *(half8*)(&As[srow][sc])     = v0;
        *(half8*)(&As[srow][sc + 8]) = v1;
        __syncthreads();
#pragma unroll
        for (int kk = 0; kk < 256; kk += 32) {
            half8 af = *(const half8*)(&As[l15][kk + lq * 8]);
#pragma unroll
            for (int nf = 0; nf < 2; ++nf) {
                half8 bf = *(const half8*)(Wt2 + (long)(n0 + nf * 16 + l15) * 4096
                                           + kbase + k0 + kk + lq * 8);
                acc[nf] = __builtin_amdgcn_mfma_f32_16x16x32_f16(af, bf, acc[nf], 0, 0, 0);
            }
        }
    }

    float* pbase = pws + (long)blockIdx.y * 262144;
#pragma unroll
    for (int nf = 0; nf < 2; ++nf) {
        int n = n0 + nf * 16 + l15;
#pragma unroll
        for (int reg = 0; reg < 4; ++reg) {
            int b = brow + lq * 4 + reg;
            pbase[(long)b * 128 + n] = acc[nf][reg];
        }
    }
}

// ---------------------------------------------------------------------------
// Kernel 3b: reduce 8 split-K partials + bias + relu -> feats fp32 + f16.
// ---------------------------------------------------------------------------
__global__ __launch_bounds__(256) void k_dense_reduce(
    const float* __restrict__ pws, const float* __restrict__ db,
    float* __restrict__ feats, _Float16* __restrict__ featsH)
{
    int t = blockIdx.x * 256 + threadIdx.x;   // 262144 total
    float acc = db[t & 127];
#pragma unroll
    for (int kc = 0; kc < 8; ++kc)
        acc += pws[(long)kc * 262144 + t];
    float val = fmaxf(acc, 0.f);
    feats[t] = val;
    featsH[t] = (_Float16)val;
}

// ---------------------------------------------------------------------------
// Kernel 4: router MLP + softmax.
// ---------------------------------------------------------------------------
__global__ __launch_bounds__(64) void k_router(
    const float* __restrict__ feats,
    const float* __restrict__ rW1, const float* __restrict__ rb1,
    const float* __restrict__ rW2, const float* __restrict__ rb2,
    float* __restrict__ probs)
{
    __shared__ float f[128];
    __shared__ float r1[64];
    __shared__ float lg[16];
    int b = blockIdx.x, tid = threadIdx.x;

    f[tid]      = feats[(long)b * 128 + tid];
    f[tid + 64] = feats[(long)b * 128 + 64 + tid];
    __syncthreads();

    float acc = rb1[tid];
#pragma unroll 8
    for (int d = 0; d < 128; ++d) acc += f[d] * rW1[d * 64 + tid];
    r1[tid] = fmaxf(acc, 0.f);
    __syncthreads();

    if (tid < 16) {
        float a = rb2[tid];
#pragma unroll 8
        for (int k = 0; k < 64; ++k) a += r1[k] * rW2[k * 16 + tid];
        lg[tid] = a;
    }
    __syncthreads();

    if (tid == 0) {
        float mx = lg[0];
#pragma unroll
        for (int i = 1; i < 16; ++i) mx = fmaxf(mx, lg[i]);
        float s = 0.f, e[16];
#pragma unroll
        for (int i = 0; i < 16; ++i) { e[i] = __expf(lg[i] - mx); s += e[i]; }
        float inv = 1.f / s;
#pragma unroll
        for (int i = 0; i < 16; ++i) probs[(long)b * 16 + i] = e[i] * inv;
    }
}

// ---------------------------------------------------------------------------
// Kernel 5: fused expert chain, f16 MFMA.
// Grid (16 experts, 32 b-tiles of 64). 4 waves x 16 rows each.
// e3p output: [16][2048][16] fp32 (cols 10..15 exactly 0).
// ---------------------------------------------------------------------------
__global__ __launch_bounds__(256) void k_expert_mfma(
    const _Float16* __restrict__ featsH,
    const _Float16* __restrict__ eW1t, const float* __restrict__ eb1,
    const float* __restrict__ g,  const float* __restrict__ bb,
    const float* __restrict__ m,  const float* __restrict__ v,
    const _Float16* __restrict__ eW2t, const float* __restrict__ eb2,
    const _Float16* __restrict__ eW3p, const float* __restrict__ eb3,
    float* __restrict__ e3p)
{
    __shared__ __align__(16) _Float16 fsH[64][136];
    __shared__ __align__(16) _Float16 h1sH[64][136];
    __shared__ __align__(16) _Float16 h2sH[64][72];
    int e = blockIdx.x, bt = blockIdx.y;
    int tid = threadIdx.x;
    int w = tid >> 6, l = tid & 63, l15 = l & 15, lq = l >> 4;
    int brow = bt * 64, m0 = w * 16;

#pragma unroll
    for (int it = 0; it < 4; ++it) {
        int idx = it * 256 + tid;
        int r = idx >> 4, c = (idx & 15) * 8;
        *(half8*)&fsH[r][c] = *(const half8*)(featsH + (long)(brow + r) * 128 + c);
    }
    __syncthreads();

    // phase 1: [64x128] @ [128x128] + BN + relu
    {
        half8 af[4];
#pragma unroll
        for (int kq = 0; kq < 4; ++kq)
            af[kq] = *(const half8*)&fsH[m0 + l15][kq * 32 + lq * 8];
        const _Float16* B1 = eW1t + (long)e * 16384 + l15 * 128 + lq * 8;
        f32x4 acc[8];
#pragma unroll
        for (int nf = 0; nf < 8; ++nf) {
            float bv = eb1[e * 128 + nf * 16 + l15];
            acc[nf] = (f32x4){ bv, bv, bv, bv };
        }
#pragma unroll
        for (int nf = 0; nf < 8; ++nf)
#pragma unroll
            for (int kq = 0; kq < 4; ++kq) {
                half8 bfv = *(const half8*)(B1 + nf * 2048 + kq * 32);
                acc[nf] = __builtin_amdgcn_mfma_f32_16x16x32_f16(af[kq], bfv, acc[nf], 0, 0, 0);
            }
#pragma unroll
        for (int nf = 0; nf < 8; ++nf) {
            int h = nf * 16 + l15;
            float gg = g[e * 128 + h], bbv = bb[e * 128 + h], mm = m[e * 128 + h];
            float iv = rsqrtf(v[e * 128 + h] + EPS);
#pragma unroll
            for (int reg = 0; reg < 4; ++reg) {
                float val = fmaxf(acc[nf][reg], 0.f);
                h1sH[m0 + lq * 4 + reg][h] = (_Float16)((val - mm) * iv * gg + bbv);
            }
        }
    }
    __syncthreads();

    // phase 2: [64x128] @ [128x64] + relu
    {
        half8 af[4];
#pragma unroll
        for (int kq = 0; kq < 4; ++kq)
            af[kq] = *(const half8*)&h1sH[m0 + l15][kq * 32 + lq * 8];
        const _Float16* B2 = eW2t + (long)e * 8192 + l15 * 128 + lq * 8;
        f32x4 acc[4];
#pragma unroll
        for (int nf = 0; nf < 4; ++nf) {
            float bv = eb2[e * 64 + nf * 16 + l15];
            acc[nf] = (f32x4){ bv, bv, bv, bv };
        }
#pragma unroll
        for (int nf = 0; nf < 4; ++nf)
#pragma unroll
            for (int kq = 0; kq < 4; ++kq) {
                half8 bfv = *(const half8*)(B2 + nf * 2048 + kq * 32);
                acc[nf] = __builtin_amdgcn_mfma_f32_16x16x32_f16(af[kq], bfv, acc[nf], 0, 0, 0);
            }
#pragma unroll
        for (int nf = 0; nf < 4; ++nf)
#pragma unroll
            for (int reg = 0; reg < 4; ++reg)
                h2sH[m0 + lq * 4 + reg][nf * 16 + l15] = (_Float16)fmaxf(acc[nf][reg], 0.f);
    }
    __syncthreads();

    // phase 3: [64x64] @ [64x16(pad)] -> e3p
    {
        half8 af[2];
#pragma unroll
        for (int kq = 0; kq < 2; ++kq)
            af[kq] = *(const half8*)&h2sH[m0 + l15][kq * 32 + lq * 8];
        const _Float16* B3 = eW3p + (long)e * 1024 + l15 * 64 + lq * 8;
        float bv = (l15 < 10) ? eb3[e * 10 + l15] : 0.f;
        f32x4 acc = (f32x4){ bv, bv, bv, bv };
#pragma unroll
        for (int kq = 0; kq < 2; ++kq) {
            half8 bfv = *(const half8*)(B3 + kq * 32);
            acc = __builtin_amdgcn_mfma_f32_16x16x32_f16(af[kq], bfv, acc, 0, 0, 0);
        }
#pragma unroll
        for (int reg = 0; reg < 4; ++reg) {
            int b = brow + m0 + lq * 4 + reg;
            e3p[((long)e * 2048 + b) * 16 + l15] = acc[reg];
        }
    }
}

// ---------------------------------------------------------------------------
// Kernel 6: combine.  out[b][c] = sum_e probs[b][e] * e3p[e][b][c]
// ---------------------------------------------------------------------------
__global__ __launch_bounds__(256) void k_combine(
    const float* __restrict__ e3p, const float* __restrict__ probs,
    float* __restrict__ out)
{
    int t = blockIdx.x * blockDim.x + threadIdx.x;
    if (t >= 2048 * 10) return;
    int b = t / 10, c = t % 10;
    float acc = 0.f;
#pragma unroll
    for (int e = 0; e < 16; ++e)
        acc += probs[(long)b * 16 + e] * e3p[((long)e * 2048 + b) * 16 + c];
    out[t] = acc;
}

// ---------------------------------------------------------------------------
extern "C" void kernel_launch(void* const* d_in, const int* in_sizes, int n_in,
                              void* d_out, int out_size, void* d_ws, size_t ws_size,
                              hipStream_t stream)
{
    const float* x    = (const float*)d_in[0];
    const float* cW1  = (const float*)d_in[1];
    const float* cb1  = (const float*)d_in[2];
    const float* bn1g = (const float*)d_in[3];
    const float* bn1b = (const float*)d_in[4];
    const float* bn1m = (const float*)d_in[5];
    const float* bn1v = (const float*)d_in[6];
    const float* cW2  = (const float*)d_in[7];
    const float* cb2  = (const float*)d_in[8];
    const float* bn2g = (const float*)d_in[9];
    const float* bn2b = (const float*)d_in[10];
    const float* bn2m = (const float*)d_in[11];
    const float* bn2v = (const float*)d_in[12];
    const float* dW   = (const float*)d_in[13];
    const float* db   = (const float*)d_in[14];
    const float* rW1  = (const float*)d_in[15];
    const float* rb1  = (const float*)d_in[16];
    const float* rW2  = (const float*)d_in[17];
    const float* rb2  = (const float*)d_in[18];
    const float* eW1  = (const float*)d_in[19];
    const float* eb1  = (const float*)d_in[20];
    const float* ebng = (const float*)d_in[21];
    const float* ebnb = (const float*)d_in[22];
    const float* ebnm = (const float*)d_in[23];
    const float* ebnv = (const float*)d_in[24];
    const float* eW2  = (const float*)d_in[25];
    const float* eb2  = (const float*)d_in[26];
    const float* eW3  = (const float*)d_in[27];
    const float* eb3  = (const float*)d_in[28];

    float* ws    = (float*)d_ws;
    // --- region 1: h1reg (16,777,216 float slots) ---
    float* h1reg = ws;
    _Float16* h1f = (_Float16*)h1reg;      // conv1 out f16, 16.7M f16
    // After conv2 consumes h1f, this region is recycled:
    float* e3p   = h1reg;                                  // [0 .. 524,288) floats
    _Float16* featsH = (_Float16*)(h1reg + 524288);        // 262,144 f16
    // --- region 2: h2reg (8,388,608 float slots) ---
    float* h2reg = h1reg + 16777216;
    _Float16* h2f = (_Float16*)h2reg;                      // conv2 out f16 [2048][4096]
    _Float16* Wt2 = (_Float16*)(h2reg + 4194304);          // dense weights f16 [128][4096]
    // --- region 3: small tensors ---
    float* feats = h2reg + 8388608;        //    262,144 floats
    float* probs = feats + 262144;         //     32,768 floats
    float* ewreg = probs + 32768;          //    262,144 floats reserved
    _Float16* eW1t = (_Float16*)ewreg;             // 262,144 f16
    _Float16* eW2t = eW1t + 262144;                // 131,072 f16
    _Float16* eW3p = eW2t + 131072;                //  16,384 f16
    _Float16* Wt   = eW3p + 16384;                 //  18,432 f16 (conv2 w)
    _Float16* Wt1  = Wt + 18432;                   //   3,072 f16 (conv1 w)
    // --- region 4: dense split-K partials [8][2048][128] fp32 = 8 MB ---
    float* pws   = ewreg + 262144;
    float* out   = (float*)d_out;

    k_wprep_small<<<148, 256, 0, stream>>>(cW1, cW2, eW3, Wt1, Wt, eW3p);
    k_wprep2<<<64, 256, 0, stream>>>(dW, Wt2);
    k_wprep_e1<<<16, 256, 0, stream>>>(eW1, eW1t);
    k_wprep_e2<<<16, 256, 0, stream>>>(eW2, eW2t);
    k_conv1_mfma<<<2048, 256, 0, stream>>>(x, Wt1, cb1, bn1g, bn1b, bn1m, bn1v, h1f);
    k_conv2_mfma<<<2048, 256, 0, stream>>>(h1f, Wt, cb2, bn2g, bn2b, bn2m, bn2v, h2f);
    {
        dim3 grid(128, 8);
        k_dense_mfma<<<grid, 256, 0, stream>>>(h2f, Wt2, pws);
    }
    k_dense_reduce<<<1024, 256, 0, stream>>>(pws, db, feats, featsH);
    k_router<<<2048, 64, 0, stream>>>(feats, rW1, rb1, rW2, rb2, probs);
    {
        dim3 grid(16, 32);
        k_expert_mfma<<<grid, 256, 0, stream>>>(featsH, eW1t, eb1, ebng, ebnb, ebnm, ebnv,
                                                eW2t, eb2, eW3p, eb3, e3p);
    }
    k_combine<<<80, 256, 0, stream>>>(e3p, probs, out);
}

// Round 8
// 104.258 us; speedup vs baseline: 10.3427x; 1.1198x over previous
//
#include <hip/hip_runtime.h>

#define EPS 1e-3f

typedef _Float16 half8 __attribute__((ext_vector_type(8)));
typedef _Float16 half4v __attribute__((ext_vector_type(4)));
typedef float f32x4 __attribute__((ext_vector_type(4)));

// ---------------------------------------------------------------------------
// Merged weight prep (single dispatch), branch by block range:
//  blocks [0,64):   dW fp32 [4096][128] -> Wt2 f16 [128][4096]        (LDS transpose)
//  blocks [64,80):  eW1 [16][128d][128h] -> eW1t f16 [16][128h][128d] (LDS transpose)
//  blocks [80,96):  eW2 [16][128h][64k]  -> eW2t f16 [16][64k][128h]  (LDS transpose)
//  blocks [96,244): cW1 -> Wt1 [3ky][32co][32k] (k=kx*4+ci, zero-pad)
//                   cW2 -> Wt  [9tap][64co][32ci]
//                   eW3 -> eW3p [16][16n(pad0)][64k]
// ---------------------------------------------------------------------------
__global__ __launch_bounds__(256) void k_wprep_all(
    const float* __restrict__ dW,  _Float16* __restrict__ Wt2,
    const float* __restrict__ eW1, _Float16* __restrict__ eW1t,
    const float* __restrict__ eW2, _Float16* __restrict__ eW2t,
    const float* __restrict__ cW1, _Float16* __restrict__ Wt1,
    const float* __restrict__ cW2, _Float16* __restrict__ Wt,
    const float* __restrict__ eW3, _Float16* __restrict__ eW3p)
{
    __shared__ _Float16 lsbuf[16640];   // max of the three transpose tiles
    int bx = blockIdx.x, tid = threadIdx.x;

    if (bx < 64) {
        auto lt = (_Float16(*)[137])lsbuf;       // [64][137]
        int kb = bx * 64;
        int c = tid & 127, r2 = tid >> 7;
#pragma unroll
        for (int it = 0; it < 32; ++it) {
            int r = it * 2 + r2;
            lt[r][c] = (_Float16)dW[(long)(kb + r) * 128 + c];
        }
        __syncthreads();
#pragma unroll
        for (int it = 0; it < 4; ++it) {
            int chunk = it * 256 + tid;
            int n = chunk >> 3, kc = (chunk & 7) * 8;
            half8 v;
#pragma unroll
            for (int j = 0; j < 8; ++j) v[j] = lt[kc + j][n];
            *(half8*)(Wt2 + (long)n * 4096 + kb + kc) = v;
        }
    } else if (bx < 80) {
        auto lt = (_Float16(*)[130])lsbuf;       // [128][130]
        int e = bx - 64;
        const float* src = eW1 + (long)e * 16384;
#pragma unroll
        for (int it = 0; it < 64; ++it) {
            int idx = it * 256 + tid;
            lt[idx >> 7][idx & 127] = (_Float16)src[idx];
        }
        __syncthreads();
        _Float16* dst = eW1t + (long)e * 16384;
#pragma unroll
        for (int it = 0; it < 64; ++it) {
            int idx = it * 256 + tid;            // idx = h*128 + d
            dst[idx] = lt[idx & 127][idx >> 7];
        }
    } else if (bx < 96) {
        auto lt = (_Float16(*)[66])lsbuf;        // [128][66]
        int e = bx - 80;
        const float* src = eW2 + (long)e * 8192;
#pragma unroll
        for (int it = 0; it < 32; ++it) {
            int idx = it * 256 + tid;
            lt[idx >> 6][idx & 63] = (_Float16)src[idx];
        }
        __syncthreads();
        _Float16* dst = eW2t + (long)e * 8192;
#pragma unroll
        for (int it = 0; it < 32; ++it) {
            int idx = it * 256 + tid;            // idx = n*128 + d
            dst[idx] = lt[idx & 127][idx >> 7];
        }
    } else {
        int t = (bx - 96) * 256 + tid;
        if (t < 3072) {
            int k = t & 31, co = (t >> 5) & 31, ky = t >> 10;
            int kx = k >> 2, ci = k & 3;
            float val = (kx < 3 && ci < 3) ? cW1[((ky * 3 + kx) * 3 + ci) * 32 + co] : 0.f;
            Wt1[t] = (_Float16)val;
        } else if (t < 3072 + 18432) {
            int u = t - 3072;
            int co = u & 63;
            int rest = u >> 6;
            int ci = rest & 31, tap = rest >> 5;
            Wt[(tap * 64 + co) * 32 + ci] = (_Float16)cW2[u];
        } else if (t < 3072 + 18432 + 16384) {
            int u = t - 21504;
            int k = u & 63, n = (u >> 6) & 15, e = u >> 10;
            float val = (n < 10) ? eW3[(e * 64 + k) * 10 + n] : 0.f;
            eW3p[(e * 16 + n) * 64 + k] = (_Float16)val;
        }
    }
}

// ---------------------------------------------------------------------------
// Kernel 1: conv1 as implicit-GEMM f16 MFMA. One block per image.
// ---------------------------------------------------------------------------
__global__ __launch_bounds__(256) void k_conv1_mfma(
    const float* __restrict__ x, const _Float16* __restrict__ Wt1,
    const float* __restrict__ bias,
    const float* __restrict__ g, const float* __restrict__ bb,
    const float* __restrict__ m, const float* __restrict__ v,
    _Float16* __restrict__ out)
{
    __shared__ __align__(16) _Float16 As[34][40][4];
    int tid = threadIdx.x;
    int b = blockIdx.x;
    int w = tid >> 6, l = tid & 63;
    int l15 = l & 15, lq = l >> 4;

    {
        float4 z = make_float4(0.f, 0.f, 0.f, 0.f);
        float4* flat = (float4*)&As[0][0][0];
        for (int i = tid; i < 680; i += 256) flat[i] = z;
    }
    __syncthreads();

    {
        int y = tid >> 3, x0 = (tid & 7) * 4;
        const float* src = x + ((long)b * 1024 + y * 32 + x0) * 3;
        float4 f0 = *(const float4*)(src);
        float4 f1 = *(const float4*)(src + 4);
        float4 f2 = *(const float4*)(src + 8);
        half4v h0 = { (_Float16)f0.x, (_Float16)f0.y, (_Float16)f0.z, (_Float16)0.f };
        half4v h1 = { (_Float16)f0.w, (_Float16)f1.x, (_Float16)f1.y, (_Float16)0.f };
        half4v h2 = { (_Float16)f1.z, (_Float16)f1.w, (_Float16)f2.x, (_Float16)0.f };
        half4v h3 = { (_Float16)f2.y, (_Float16)f2.z, (_Float16)f2.w, (_Float16)0.f };
        *(half4v*)&As[y + 1][x0 + 1][0] = h0;
        *(half4v*)&As[y + 1][x0 + 2][0] = h1;
        *(half4v*)&As[y + 1][x0 + 3][0] = h2;
        *(half4v*)&As[y + 1][x0 + 4][0] = h3;
    }

    half8 bf[3][2];
#pragma unroll
    for (int ky = 0; ky < 3; ++ky)
#pragma unroll
        for (int nf = 0; nf < 2; ++nf)
            bf[ky][nf] = *(const half8*)(Wt1 + (ky * 32 + nf * 16 + l15) * 32 + lq * 8);

    float bv[2], gg[2], iv[2], mm[2], bbv[2];
#pragma unroll
    for (int nf = 0; nf < 2; ++nf) {
        int co = nf * 16 + l15;
        bv[nf] = bias[co]; gg[nf] = g[co]; bbv[nf] = bb[co]; mm[nf] = m[co];
        iv[nf] = rsqrtf(v[co] + EPS);
    }
    __syncthreads();

    int y0 = w * 8;
#pragma unroll
    for (int pr = 0; pr < 4; ++pr) {
        int ya = y0 + 2 * pr;
        f32x4 acc[2][2][2];
#pragma unroll
        for (int r = 0; r < 2; ++r)
#pragma unroll
            for (int h = 0; h < 2; ++h)
#pragma unroll
                for (int nf = 0; nf < 2; ++nf)
                    acc[r][h][nf] = (f32x4){ bv[nf], bv[nf], bv[nf], bv[nf] };

#pragma unroll
        for (int ky = 0; ky < 3; ++ky)
#pragma unroll
            for (int r = 0; r < 2; ++r)
#pragma unroll
                for (int h = 0; h < 2; ++h) {
                    const _Float16* ap = &As[ya + r + ky][h * 16 + l15 + 2 * lq][0];
                    half4v a0 = *(const half4v*)ap;
                    half4v a1 = *(const half4v*)(ap + 4);
                    half8 af = __builtin_shufflevector(a0, a1, 0, 1, 2, 3, 4, 5, 6, 7);
#pragma unroll
                    for (int nf = 0; nf < 2; ++nf)
                        acc[r][h][nf] = __builtin_amdgcn_mfma_f32_16x16x32_f16(
                            af, bf[ky][nf], acc[r][h][nf], 0, 0, 0);
                }

        int py = w * 4 + pr;
#pragma unroll
        for (int h = 0; h < 2; ++h)
#pragma unroll
            for (int nf = 0; nf < 2; ++nf) {
                f32x4 aA = acc[0][h][nf], aB = acc[1][h][nf];
                float p0 = fmaxf(fmaxf(aA[0], aA[1]), fmaxf(aB[0], aB[1]));
                float p1 = fmaxf(fmaxf(aA[2], aA[3]), fmaxf(aB[2], aB[3]));
                p0 = fmaxf(p0, 0.f); p1 = fmaxf(p1, 0.f);
                p0 = (p0 - mm[nf]) * iv[nf] * gg[nf] + bbv[nf];
                p1 = (p1 - mm[nf]) * iv[nf] * gg[nf] + bbv[nf];
                int px = h * 8 + lq * 2;
                int co = nf * 16 + l15;
                long base = (((long)b * 16 + py) * 16 + px) * 32 + co;
                out[base]      = (_Float16)p0;
                out[base + 32] = (_Float16)p1;
            }
    }
}

// ---------------------------------------------------------------------------
// Kernel 2: conv2 as implicit-GEMM f16 MFMA -> h2 f16 [2048][4096]
// ---------------------------------------------------------------------------
__global__ __launch_bounds__(256) void k_conv2_mfma(
    const _Float16* __restrict__ h1f, const _Float16* __restrict__ Wt,
    const float* __restrict__ bias,
    const float* __restrict__ g, const float* __restrict__ bb,
    const float* __restrict__ m, const float* __restrict__ v,
    _Float16* __restrict__ out)
{
    __shared__ __align__(16) _Float16 As[18][18][40];
    int tid = threadIdx.x;
    int b   = blockIdx.x;
    int w   = tid >> 6;
    int l   = tid & 63;
    int l15 = l & 15, lq = l >> 4;

    {
        _Float16* flat = &As[0][0][0];
        for (int i = tid * 8; i < 18 * 18 * 40; i += 256 * 8)
            *(float4*)(flat + i) = make_float4(0.f, 0.f, 0.f, 0.f);
    }
    __syncthreads();

    {
        const _Float16* src = h1f + ((long)b * 256 + tid) * 32;
        _Float16* dst = &As[(tid >> 4) + 1][(tid & 15) + 1][0];
#pragma unroll
        for (int i = 0; i < 4; ++i)
            *(half8*)(dst + i * 8) = *(const half8*)(src + i * 8);
    }

    f32x4 acc[4][4];
#pragma unroll
    for (int nf = 0; nf < 4; ++nf) {
        float bv = bias[nf * 16 + l15];
#pragma unroll
        for (int mf = 0; mf < 4; ++mf)
            acc[mf][nf] = (f32x4){ bv, bv, bv, bv };
    }
    __syncthreads();

    int row0 = 4 * w;
#pragma unroll
    for (int tap = 0; tap < 9; ++tap) {
        int ky = tap / 3, kx = tap % 3;
        half8 bf[4];
        const _Float16* wb = Wt + ((long)(tap * 64 + l15)) * 32 + lq * 8;
#pragma unroll
        for (int nf = 0; nf < 4; ++nf)
            bf[nf] = *(const half8*)(wb + (long)nf * 16 * 32);
#pragma unroll
        for (int mf = 0; mf < 4; ++mf) {
            const _Float16* ap = &As[row0 + mf + ky][l15 + kx][lq * 8];
            half8 af = *(const half8*)ap;
#pragma unroll
            for (int nf = 0; nf < 4; ++nf)
                acc[mf][nf] = __builtin_amdgcn_mfma_f32_16x16x32_f16(
                    af, bf[nf], acc[mf][nf], 0, 0, 0);
        }
    }

#pragma unroll
    for (int nf = 0; nf < 4; ++nf) {
        int co = nf * 16 + l15;
        float gg = g[co], bbv = bb[co], mm = m[co];
        float iv = rsqrtf(v[co] + EPS);
#pragma unroll
        for (int pr = 0; pr < 2; ++pr) {
            int prow = 2 * w + pr;
            f32x4 a0 = acc[2 * pr][nf];
            f32x4 a1 = acc[2 * pr + 1][nf];
            float p0 = fmaxf(fmaxf(a0[0], a0[1]), fmaxf(a1[0], a1[1]));
            float p1 = fmaxf(fmaxf(a0[2], a0[3]), fmaxf(a1[2], a1[3]));
            p0 = fmaxf(p0, 0.f);
            p1 = fmaxf(p1, 0.f);
            int ppx = lq * 2;
            long base = (((long)b * 8 + prow) * 8) * 64 + co;
            out[base + (long)(ppx    ) * 64] = (_Float16)((p0 - mm) * iv * gg + bbv);
            out[base + (long)(ppx + 1) * 64] = (_Float16)((p1 - mm) * iv * gg + bbv);
        }
    }
}

// ---------------------------------------------------------------------------
// Kernel 3a: dense 4096 -> 128, split-K x8, f16 MFMA. No bias (added in reduce).
// Grid (128 m-tiles, 8 k-chunks of 512). Partial out: pws[kc][2048][128] fp32.
// ---------------------------------------------------------------------------
__global__ __launch_bounds__(256) void k_dense_mfma(
    const _Float16* __restrict__ h2f, const _Float16* __restrict__ Wt2,
    float* __restrict__ pws)
{
    __shared__ __align__(16) _Float16 As[16][264];
    int tid = threadIdx.x;
    int w = tid >> 6, l = tid & 63;
    int l15 = l & 15, lq = l >> 4;
    int brow = blockIdx.x * 16;
    int kbase = blockIdx.y * 512;
    int n0 = w * 32;

    f32x4 acc[2] = { (f32x4){0.f,0.f,0.f,0.f}, (f32x4){0.f,0.f,0.f,0.f} };

    int srow = tid >> 4, sc = (tid & 15) * 16;
#pragma unroll
    for (int k0 = 0; k0 < 512; k0 += 256) {
        __syncthreads();
        const _Float16* src = h2f + (long)(brow + srow) * 4096 + kbase + k0 + sc;
        half8 v0 = *(const half8*)src;
        half8 v1 = *(const half8*)(src + 8);
        *(half8*)(&As[srow][sc])     = v0;
        *(half8*)(&As[srow][sc + 8]) = v1;
        __syncthreads();
#pragma unroll
        for (int kk = 0; kk < 256; kk += 32) {
            half8 af = *(const half8*)(&As[l15][kk + lq * 8]);
#pragma unroll
            for (int nf = 0; nf < 2; ++nf) {
                half8 bf = *(const half8*)(Wt2 + (long)(n0 + nf * 16 + l15) * 4096
                                           + kbase + k0 + kk + lq * 8);
                acc[nf] = __builtin_amdgcn_mfma_f32_16x16x32_f16(af, bf, acc[nf], 0, 0, 0);
            }
        }
    }

    float* pbase = pws + (long)blockIdx.y * 262144;
#pragma unroll
    for (int nf = 0; nf < 2; ++nf) {
        int n = n0 + nf * 16 + l15;
#pragma unroll
        for (int reg = 0; reg < 4; ++reg) {
            int b = brow + lq * 4 + reg;
            pbase[(long)b * 128 + n] = acc[nf][reg];
        }
    }
}

// ---------------------------------------------------------------------------
// Kernel 3b: fused split-K reduce + bias + relu -> featsH, then router MLP
// + 16-lane-shuffle softmax -> probs. One block per 16 batch rows.
// ---------------------------------------------------------------------------
__global__ __launch_bounds__(256) void k_reduce_router(
    const float* __restrict__ pws, const float* __restrict__ db,
    const float* __restrict__ rW1, const float* __restrict__ rb1,
    const float* __restrict__ rW2, const float* __restrict__ rb2,
    _Float16* __restrict__ featsH, float* __restrict__ probs)
{
    __shared__ float fsm[16][128];
    __shared__ float r1s[16][64];
    int tid = threadIdx.x;
    int brow = blockIdx.x * 16;
    int r = tid >> 4, c0 = (tid & 15) * 8;

    // reduce 8 partials + bias + relu
    float acc[8];
#pragma unroll
    for (int j = 0; j < 8; ++j) acc[j] = db[c0 + j];
    long base = (long)(brow + r) * 128 + c0;
#pragma unroll
    for (int kc = 0; kc < 8; ++kc) {
        const float4* p = (const float4*)(pws + (long)kc * 262144 + base);
        float4 v0 = p[0], v1 = p[1];
        acc[0] += v0.x; acc[1] += v0.y; acc[2] += v0.z; acc[3] += v0.w;
        acc[4] += v1.x; acc[5] += v1.y; acc[6] += v1.z; acc[7] += v1.w;
    }
    half8 hv;
#pragma unroll
    for (int j = 0; j < 8; ++j) {
        float val = fmaxf(acc[j], 0.f);
        fsm[r][c0 + j] = val;
        hv[j] = (_Float16)val;
    }
    *(half8*)(featsH + base) = hv;
    __syncthreads();

    // router L1: h = tid&63, 4 rows per thread (LDS reads broadcast per wave)
    {
        int h = tid & 63, bg = tid >> 6;
        float a[4];
#pragma unroll
        for (int i = 0; i < 4; ++i) a[i] = rb1[h];
        for (int d = 0; d < 128; ++d) {
            float wgt = rW1[d * 64 + h];
#pragma unroll
            for (int i = 0; i < 4; ++i) a[i] += fsm[bg * 4 + i][d] * wgt;
        }
#pragma unroll
        for (int i = 0; i < 4; ++i) r1s[bg * 4 + i][h] = fmaxf(a[i], 0.f);
    }
    __syncthreads();

    // router L2 + softmax (16 lanes per row, shuffle reduce)
    {
        int b = tid >> 4, e = tid & 15;
        float a = rb2[e];
#pragma unroll 8
        for (int k = 0; k < 64; ++k) a += r1s[b][k] * rW2[k * 16 + e];
        float mx = a;
#pragma unroll
        for (int off = 1; off < 16; off <<= 1)
            mx = fmaxf(mx, __shfl_xor(mx, off, 16));
        float ex = __expf(a - mx);
        float s = ex;
#pragma unroll
        for (int off = 1; off < 16; off <<= 1)
            s += __shfl_xor(s, off, 16);
        probs[(long)(brow + b) * 16 + e] = ex / s;
    }
}

// ---------------------------------------------------------------------------
// Kernel 5: fused expert chain, f16 MFMA.
// Grid (16 experts, 32 b-tiles of 64). 4 waves x 16 rows each.
// e3p output: [16][2048][16] fp32 (cols 10..15 exactly 0).
// ---------------------------------------------------------------------------
__global__ __launch_bounds__(256) void k_expert_mfma(
    const _Float16* __restrict__ featsH,
    const _Float16* __restrict__ eW1t, const float* __restrict__ eb1,
    const float* __restrict__ g,  const float* __restrict__ bb,
    const float* __restrict__ m,  const float* __restrict__ v,
    const _Float16* __restrict__ eW2t, const float* __restrict__ eb2,
    const _Float16* __restrict__ eW3p, const float* __restrict__ eb3,
    float* __restrict__ e3p)
{
    __shared__ __align__(16) _Float16 fsH[64][136];
    __shared__ __align__(16) _Float16 h1sH[64][136];
    __shared__ __align__(16) _Float16 h2sH[64][72];
    int e = blockIdx.x, bt = blockIdx.y;
    int tid = threadIdx.x;
    int w = tid >> 6, l = tid & 63, l15 = l & 15, lq = l >> 4;
    int brow = bt * 64, m0 = w * 16;

#pragma unroll
    for (int it = 0; it < 4; ++it) {
        int idx = it * 256 + tid;
        int r = idx >> 4, c = (idx & 15) * 8;
        *(half8*)&fsH[r][c] = *(const half8*)(featsH + (long)(brow + r) * 128 + c);
    }
    __syncthreads();

    // phase 1: [64x128] @ [128x128] + BN + relu
    {
        half8 af[4];
#pragma unroll
        for (int kq = 0; kq < 4; ++kq)
            af[kq] = *(const half8*)&fsH[m0 + l15][kq * 32 + lq * 8];
        const _Float16* B1 = eW1t + (long)e * 16384 + l15 * 128 + lq * 8;
        f32x4 acc[8];
#pragma unroll
        for (int nf = 0; nf < 8; ++nf) {
            float bv = eb1[e * 128 + nf * 16 + l15];
            acc[nf] = (f32x4){ bv, bv, bv, bv };
        }
#pragma unroll
        for (int nf = 0; nf < 8; ++nf)
#pragma unroll
            for (int kq = 0; kq < 4; ++kq) {
                half8 bfv = *(const half8*)(B1 + nf * 2048 + kq * 32);
                acc[nf] = __builtin_amdgcn_mfma_f32_16x16x32_f16(af[kq], bfv, acc[nf], 0, 0, 0);
            }
#pragma unroll
        for (int nf = 0; nf < 8; ++nf) {
            int h = nf * 16 + l15;
            float gg = g[e * 128 + h], bbv = bb[e * 128 + h], mm = m[e * 128 + h];
            float iv = rsqrtf(v[e * 128 + h] + EPS);
#pragma unroll
            for (int reg = 0; reg < 4; ++reg) {
                float val = fmaxf(acc[nf][reg], 0.f);
                h1sH[m0 + lq * 4 + reg][h] = (_Float16)((val - mm) * iv * gg + bbv);
            }
        }
    }
    __syncthreads();

    // phase 2: [64x128] @ [128x64] + relu
    {
        half8 af[4];
#pragma unroll
        for (int kq = 0; kq < 4; ++kq)
            af[kq] = *(const half8*)&h1sH[m0 + l15][kq * 32 + lq * 8];
        const _Float16* B2 = eW2t + (long)e * 8192 + l15 * 128 + lq * 8;
        f32x4 acc[4];
#pragma unroll
        for (int nf = 0; nf < 4; ++nf) {
            float bv = eb2[e * 64 + nf * 16 + l15];
            acc[nf] = (f32x4){ bv, bv, bv, bv };
        }
#pragma unroll
        for (int nf = 0; nf < 4; ++nf)
#pragma unroll
            for (int kq = 0; kq < 4; ++kq) {
                half8 bfv = *(const half8*)(B2 + nf * 2048 + kq * 32);
                acc[nf] = __builtin_amdgcn_mfma_f32_16x16x32_f16(af[kq], bfv, acc[nf], 0, 0, 0);
            }
#pragma unroll
        for (int nf = 0; nf < 4; ++nf)
#pragma unroll
            for (int reg = 0; reg < 4; ++reg)
                h2sH[m0 + lq * 4 + reg][nf * 16 + l15] = (_Float16)fmaxf(acc[nf][reg], 0.f);
    }
    __syncthreads();

    // phase 3: [64x64] @ [64x16(pad)] -> e3p
    {
        half8 af[2];
#pragma unroll
        for (int kq = 0; kq < 2; ++kq)
            af[kq] = *(const half8*)&h2sH[m0 + l15][kq * 32 + lq * 8];
        const _Float16* B3 = eW3p + (long)e * 1024 + l15 * 64 + lq * 8;
        float bv = (l15 < 10) ? eb3[e * 10 + l15] : 0.f;
        f32x4 acc = (f32x4){ bv, bv, bv, bv };
#pragma unroll
        for (int kq = 0; kq < 2; ++kq) {
            half8 bfv = *(const half8*)(B3 + kq * 32);
            acc = __builtin_amdgcn_mfma_f32_16x16x32_f16(af[kq], bfv, acc, 0, 0, 0);
        }
#pragma unroll
        for (int reg = 0; reg < 4; ++reg) {
            int b = brow + m0 + lq * 4 + reg;
            e3p[((long)e * 2048 + b) * 16 + l15] = acc[reg];
        }
    }
}

// ---------------------------------------------------------------------------
// Kernel 6: combine.  out[b][c] = sum_e probs[b][e] * e3p[e][b][c]
// ---------------------------------------------------------------------------
__global__ __launch_bounds__(256) void k_combine(
    const float* __restrict__ e3p, const float* __restrict__ probs,
    float* __restrict__ out)
{
    int t = blockIdx.x * blockDim.x + threadIdx.x;
    if (t >= 2048 * 10) return;
    int b = t / 10, c = t % 10;
    float acc = 0.f;
#pragma unroll
    for (int e = 0; e < 16; ++e)
        acc += probs[(long)b * 16 + e] * e3p[((long)e * 2048 + b) * 16 + c];
    out[t] = acc;
}

// ---------------------------------------------------------------------------
extern "C" void kernel_launch(void* const* d_in, const int* in_sizes, int n_in,
                              void* d_out, int out_size, void* d_ws, size_t ws_size,
                              hipStream_t stream)
{
    const float* x    = (const float*)d_in[0];
    const float* cW1  = (const float*)d_in[1];
    const float* cb1  = (const float*)d_in[2];
    const float* bn1g = (const float*)d_in[3];
    const float* bn1b = (const float*)d_in[4];
    const float* bn1m = (const float*)d_in[5];
    const float* bn1v = (const float*)d_in[6];
    const float* cW2  = (const float*)d_in[7];
    const float* cb2  = (const float*)d_in[8];
    const float* bn2g = (const float*)d_in[9];
    const float* bn2b = (const float*)d_in[10];
    const float* bn2m = (const float*)d_in[11];
    const float* bn2v = (const float*)d_in[12];
    const float* dW   = (const float*)d_in[13];
    const float* db   = (const float*)d_in[14];
    const float* rW1  = (const float*)d_in[15];
    const float* rb1  = (const float*)d_in[16];
    const float* rW2  = (const float*)d_in[17];
    const float* rb2  = (const float*)d_in[18];
    const float* eW1  = (const float*)d_in[19];
    const float* eb1  = (const float*)d_in[20];
    const float* ebng = (const float*)d_in[21];
    const float* ebnb = (const float*)d_in[22];
    const float* ebnm = (const float*)d_in[23];
    const float* ebnv = (const float*)d_in[24];
    const float* eW2  = (const float*)d_in[25];
    const float* eb2  = (const float*)d_in[26];
    const float* eW3  = (const float*)d_in[27];
    const float* eb3  = (const float*)d_in[28];

    float* ws    = (float*)d_ws;
    // --- region 1: h1reg (16,777,216 float slots) ---
    float* h1reg = ws;
    _Float16* h1f = (_Float16*)h1reg;      // conv1 out f16, 16.7M f16
    // After conv2 consumes h1f, this region is recycled:
    float* e3p   = h1reg;                                  // [0 .. 524,288) floats
    _Float16* featsH = (_Float16*)(h1reg + 524288);        // 262,144 f16
    // --- region 2: h2reg (8,388,608 float slots) ---
    float* h2reg = h1reg + 16777216;
    _Float16* h2f = (_Float16*)h2reg;                      // conv2 out f16 [2048][4096]
    _Float16* Wt2 = (_Float16*)(h2reg + 4194304);          // dense weights f16 [128][4096]
    // --- region 3: small tensors ---
    float* probs = h2reg + 8388608;        //     32,768 floats
    float* ewreg = probs + 32768;
    _Float16* eW1t = (_Float16*)ewreg;             // 262,144 f16
    _Float16* eW2t = eW1t + 262144;                // 131,072 f16
    _Float16* eW3p = eW2t + 131072;                //  16,384 f16
    _Float16* Wt   = eW3p + 16384;                 //  18,432 f16 (conv2 w)
    _Float16* Wt1  = Wt + 18432;                   //   3,072 f16 (conv1 w)
    // --- region 4: dense split-K partials [8][2048][128] fp32 = 8 MB ---
    float* pws   = ewreg + 262144;
    float* out   = (float*)d_out;

    k_wprep_all<<<244, 256, 0, stream>>>(dW, Wt2, eW1, eW1t, eW2, eW2t,
                                         cW1, Wt1, cW2, Wt, eW3, eW3p);
    k_conv1_mfma<<<2048, 256, 0, stream>>>(x, Wt1, cb1, bn1g, bn1b, bn1m, bn1v, h1f);
    k_conv2_mfma<<<2048, 256, 0, stream>>>(h1f, Wt, cb2, bn2g, bn2b, bn2m, bn2v, h2f);
    {
        dim3 grid(128, 8);
        k_dense_mfma<<<grid, 256, 0, stream>>>(h2f, Wt2, pws);
    }
    k_reduce_router<<<128, 256, 0, stream>>>(pws, db, rW1, rb1, rW2, rb2,
                                             featsH, probs);
    {
        dim3 grid(16, 32);
        k_expert_mfma<<<grid, 256, 0, stream>>>(featsH, eW1t, eb1, ebng, ebnb, ebnm, ebnv,
                                                eW2t, eb2, eW3p, eb3, e3p);
    }
    k_combine<<<80, 256, 0, stream>>>(e3p, probs, out);
}

// Round 10
// 88.097 us; speedup vs baseline: 12.2400x; 1.1834x over previous
//
#include <hip/hip_runtime.h>

#define EPS 1e-3f

typedef _Float16 half8 __attribute__((ext_vector_type(8)));
typedef _Float16 half4v __attribute__((ext_vector_type(4)));
typedef float f32x4 __attribute__((ext_vector_type(4)));

// ---------------------------------------------------------------------------
// Merged weight prep (single dispatch), branch by block range:
//  blocks [0,64):   dW fp32 [4096][128] -> Wt2 f16 [128][4096]        (LDS transpose)
//  blocks [64,80):  eW1 [16][128d][128h] -> eW1t f16 [16][128h][128d] (LDS transpose)
//  blocks [80,96):  eW2 [16][128h][64k]  -> eW2t f16 [16][64k][128h]  (LDS transpose)
//  blocks [96,244): cW1 -> Wt1 [3ky][32co][32k] (k=kx*4+ci, zero-pad)
//                   cW2 -> Wt  [9tap][64co][32ci]
//                   eW3 -> eW3p [16][16n(pad0)][64k]
// ---------------------------------------------------------------------------
__global__ __launch_bounds__(256) void k_wprep_all(
    const float* __restrict__ dW,  _Float16* __restrict__ Wt2,
    const float* __restrict__ eW1, _Float16* __restrict__ eW1t,
    const float* __restrict__ eW2, _Float16* __restrict__ eW2t,
    const float* __restrict__ cW1, _Float16* __restrict__ Wt1,
    const float* __restrict__ cW2, _Float16* __restrict__ Wt,
    const float* __restrict__ eW3, _Float16* __restrict__ eW3p)
{
    __shared__ _Float16 lsbuf[16640];
    int bx = blockIdx.x, tid = threadIdx.x;

    if (bx < 64) {
        auto lt = (_Float16(*)[137])lsbuf;       // [64][137]
        int kb = bx * 64;
        int c = tid & 127, r2 = tid >> 7;
#pragma unroll
        for (int it = 0; it < 32; ++it) {
            int r = it * 2 + r2;
            lt[r][c] = (_Float16)dW[(long)(kb + r) * 128 + c];
        }
        __syncthreads();
#pragma unroll
        for (int it = 0; it < 4; ++it) {
            int chunk = it * 256 + tid;
            int n = chunk >> 3, kc = (chunk & 7) * 8;
            half8 v;
#pragma unroll
            for (int j = 0; j < 8; ++j) v[j] = lt[kc + j][n];
            *(half8*)(Wt2 + (long)n * 4096 + kb + kc) = v;
        }
    } else if (bx < 80) {
        auto lt = (_Float16(*)[130])lsbuf;       // [128][130]
        int e = bx - 64;
        const float* src = eW1 + (long)e * 16384;
#pragma unroll
        for (int it = 0; it < 64; ++it) {
            int idx = it * 256 + tid;
            lt[idx >> 7][idx & 127] = (_Float16)src[idx];
        }
        __syncthreads();
        _Float16* dst = eW1t + (long)e * 16384;
#pragma unroll
        for (int it = 0; it < 64; ++it) {
            int idx = it * 256 + tid;            // idx = h*128 + d
            dst[idx] = lt[idx & 127][idx >> 7];
        }
    } else if (bx < 96) {
        auto lt = (_Float16(*)[66])lsbuf;        // [128][66]
        int e = bx - 80;
        const float* src = eW2 + (long)e * 8192;
#pragma unroll
        for (int it = 0; it < 32; ++it) {
            int idx = it * 256 + tid;
            lt[idx >> 6][idx & 63] = (_Float16)src[idx];
        }
        __syncthreads();
        _Float16* dst = eW2t + (long)e * 8192;
#pragma unroll
        for (int it = 0; it < 32; ++it) {
            int idx = it * 256 + tid;            // idx = n*128 + d
            dst[idx] = lt[idx & 127][idx >> 7];
        }
    } else {
        int t = (bx - 96) * 256 + tid;
        if (t < 3072) {
            int k = t & 31, co = (t >> 5) & 31, ky = t >> 10;
            int kx = k >> 2, ci = k & 3;
            float val = (kx < 3 && ci < 3) ? cW1[((ky * 3 + kx) * 3 + ci) * 32 + co] : 0.f;
            Wt1[t] = (_Float16)val;
        } else if (t < 3072 + 18432) {
            int u = t - 3072;
            int co = u & 63;
            int rest = u >> 6;
            int ci = rest & 31, tap = rest >> 5;
            Wt[(tap * 64 + co) * 32 + ci] = (_Float16)cW2[u];
        } else if (t < 3072 + 18432 + 16384) {
            int u = t - 21504;
            int k = u & 63, n = (u >> 6) & 15, e = u >> 10;
            float val = (n < 10) ? eW3[(e * 64 + k) * 10 + n] : 0.f;
            eW3p[(e * 16 + n) * 64 + k] = (_Float16)val;
        }
    }
}

// ---------------------------------------------------------------------------
// Fused conv1+conv2, f16 MFMA, one block per image.
// Phase A (conv1): x [32,32,3] -> MFMA over [3ky][K=32] -> pool+relu+BN ->
//   h1 tile written DIRECTLY into As2 LDS [18][18][40] (halo zero).
// Phase B (conv2): implicit-GEMM from As2, 9 taps -> pool+relu+BN ->
//   h2f [2048][4096] f16 global.
// ---------------------------------------------------------------------------
__global__ __launch_bounds__(256) void k_conv12(
    const float* __restrict__ x, const _Float16* __restrict__ Wt1,
    const float* __restrict__ b1, const float* __restrict__ g1,
    const float* __restrict__ bb1, const float* __restrict__ m1,
    const float* __restrict__ v1,
    const _Float16* __restrict__ Wt,
    const float* __restrict__ b2, const float* __restrict__ g2,
    const float* __restrict__ bb2, const float* __restrict__ m2,
    const float* __restrict__ v2,
    _Float16* __restrict__ out)
{
    __shared__ __align__(16) _Float16 As1[34][40][4];   // conv1 input (halo, ci pad): 680 float4
    __shared__ __align__(16) _Float16 As2[18][18][40];  // h1 tile (halo): 1620 float4
    int tid = threadIdx.x;
    int b = blockIdx.x;
    int w = tid >> 6, l = tid & 63;
    int l15 = l & 15, lq = l >> 4;

    // zero both LDS arrays (halos must be 0)
    {
        float4 z = make_float4(0.f, 0.f, 0.f, 0.f);
        float4* f1p = (float4*)&As1[0][0][0];
        for (int i = tid; i < 680; i += 256) f1p[i] = z;
        float4* f2p = (float4*)&As2[0][0][0];
        for (int i = tid; i < 1620; i += 256) f2p[i] = z;   // FIXED: was 810 (half of As2)
    }
    __syncthreads();

    // stage x: 4 pixels per thread (12 contiguous floats)
    {
        int y = tid >> 3, x0 = (tid & 7) * 4;
        const float* src = x + ((long)b * 1024 + y * 32 + x0) * 3;
        float4 f0 = *(const float4*)(src);
        float4 f1 = *(const float4*)(src + 4);
        float4 f2 = *(const float4*)(src + 8);
        half4v h0 = { (_Float16)f0.x, (_Float16)f0.y, (_Float16)f0.z, (_Float16)0.f };
        half4v h1 = { (_Float16)f0.w, (_Float16)f1.x, (_Float16)f1.y, (_Float16)0.f };
        half4v h2 = { (_Float16)f1.z, (_Float16)f1.w, (_Float16)f2.x, (_Float16)0.f };
        half4v h3 = { (_Float16)f2.y, (_Float16)f2.z, (_Float16)f2.w, (_Float16)0.f };
        *(half4v*)&As1[y + 1][x0 + 1][0] = h0;
        *(half4v*)&As1[y + 1][x0 + 2][0] = h1;
        *(half4v*)&As1[y + 1][x0 + 3][0] = h2;
        *(half4v*)&As1[y + 1][x0 + 4][0] = h3;
    }

    // conv1 B-frags + BN consts
    half8 bf1[3][2];
#pragma unroll
    for (int ky = 0; ky < 3; ++ky)
#pragma unroll
        for (int nf = 0; nf < 2; ++nf)
            bf1[ky][nf] = *(const half8*)(Wt1 + (ky * 32 + nf * 16 + l15) * 32 + lq * 8);

    float bv1[2], gg1[2], iv1[2], mm1[2], bbv1[2];
#pragma unroll
    for (int nf = 0; nf < 2; ++nf) {
        int co = nf * 16 + l15;
        bv1[nf] = b1[co]; gg1[nf] = g1[co]; bbv1[nf] = bb1[co]; mm1[nf] = m1[co];
        iv1[nf] = rsqrtf(v1[co] + EPS);
    }
    __syncthreads();

    // ---- Phase A: conv1 MFMAs, pool+relu+BN -> As2 ----
    {
        int y0 = w * 8;
#pragma unroll
        for (int pr = 0; pr < 4; ++pr) {
            int ya = y0 + 2 * pr;
            f32x4 acc[2][2][2];
#pragma unroll
            for (int r = 0; r < 2; ++r)
#pragma unroll
                for (int h = 0; h < 2; ++h)
#pragma unroll
                    for (int nf = 0; nf < 2; ++nf)
                        acc[r][h][nf] = (f32x4){ bv1[nf], bv1[nf], bv1[nf], bv1[nf] };

#pragma unroll
            for (int ky = 0; ky < 3; ++ky)
#pragma unroll
                for (int r = 0; r < 2; ++r)
#pragma unroll
                    for (int h = 0; h < 2; ++h) {
                        const _Float16* ap = &As1[ya + r + ky][h * 16 + l15 + 2 * lq][0];
                        half4v a0 = *(const half4v*)ap;
                        half4v a1 = *(const half4v*)(ap + 4);
                        half8 af = __builtin_shufflevector(a0, a1, 0, 1, 2, 3, 4, 5, 6, 7);
#pragma unroll
                        for (int nf = 0; nf < 2; ++nf)
                            acc[r][h][nf] = __builtin_amdgcn_mfma_f32_16x16x32_f16(
                                af, bf1[ky][nf], acc[r][h][nf], 0, 0, 0);
                    }

            int py = w * 4 + pr;
#pragma unroll
            for (int h = 0; h < 2; ++h)
#pragma unroll
                for (int nf = 0; nf < 2; ++nf) {
                    f32x4 aA = acc[0][h][nf], aB = acc[1][h][nf];
                    float p0 = fmaxf(fmaxf(aA[0], aA[1]), fmaxf(aB[0], aB[1]));
                    float p1 = fmaxf(fmaxf(aA[2], aA[3]), fmaxf(aB[2], aB[3]));
                    p0 = fmaxf(p0, 0.f); p1 = fmaxf(p1, 0.f);
                    p0 = (p0 - mm1[nf]) * iv1[nf] * gg1[nf] + bbv1[nf];
                    p1 = (p1 - mm1[nf]) * iv1[nf] * gg1[nf] + bbv1[nf];
                    int px = h * 8 + lq * 2;
                    int co = nf * 16 + l15;
                    As2[py + 1][px + 1][co] = (_Float16)p0;
                    As2[py + 1][px + 2][co] = (_Float16)p1;
                }
        }
    }
    __syncthreads();

    // ---- Phase B: conv2 from As2 ----
    f32x4 acc2[4][4];
#pragma unroll
    for (int nf = 0; nf < 4; ++nf) {
        float bv = b2[nf * 16 + l15];
#pragma unroll
        for (int mf = 0; mf < 4; ++mf)
            acc2[mf][nf] = (f32x4){ bv, bv, bv, bv };
    }

    int row0 = 4 * w;
#pragma unroll
    for (int tap = 0; tap < 9; ++tap) {
        int ky = tap / 3, kx = tap % 3;
        half8 bf[4];
        const _Float16* wb = Wt + ((long)(tap * 64 + l15)) * 32 + lq * 8;
#pragma unroll
        for (int nf = 0; nf < 4; ++nf)
            bf[nf] = *(const half8*)(wb + (long)nf * 16 * 32);
#pragma unroll
        for (int mf = 0; mf < 4; ++mf) {
            const _Float16* ap = &As2[row0 + mf + ky][l15 + kx][lq * 8];
            half8 af = *(const half8*)ap;
#pragma unroll
            for (int nf = 0; nf < 4; ++nf)
                acc2[mf][nf] = __builtin_amdgcn_mfma_f32_16x16x32_f16(
                    af, bf[nf], acc2[mf][nf], 0, 0, 0);
        }
    }

#pragma unroll
    for (int nf = 0; nf < 4; ++nf) {
        int co = nf * 16 + l15;
        float gg = g2[co], bbv = bb2[co], mm = m2[co];
        float iv = rsqrtf(v2[co] + EPS);
#pragma unroll
        for (int pr = 0; pr < 2; ++pr) {
            int prow = 2 * w + pr;
            f32x4 a0 = acc2[2 * pr][nf];
            f32x4 a1 = acc2[2 * pr + 1][nf];
            float p0 = fmaxf(fmaxf(a0[0], a0[1]), fmaxf(a1[0], a1[1]));
            float p1 = fmaxf(fmaxf(a0[2], a0[3]), fmaxf(a1[2], a1[3]));
            p0 = fmaxf(p0, 0.f);
            p1 = fmaxf(p1, 0.f);
            int ppx = lq * 2;
            long base = (((long)b * 8 + prow) * 8) * 64 + co;
            out[base + (long)(ppx    ) * 64] = (_Float16)((p0 - mm) * iv * gg + bbv);
            out[base + (long)(ppx + 1) * 64] = (_Float16)((p1 - mm) * iv * gg + bbv);
        }
    }
}

// ---------------------------------------------------------------------------
// Kernel 3a: dense 4096 -> 128, split-K x8, f16 MFMA. No bias (added in reduce).
// ---------------------------------------------------------------------------
__global__ __launch_bounds__(256) void k_dense_mfma(
    const _Float16* __restrict__ h2f, const _Float16* __restrict__ Wt2,
    float* __restrict__ pws)
{
    __shared__ __align__(16) _Float16 As[16][264];
    int tid = threadIdx.x;
    int w = tid >> 6, l = tid & 63;
    int l15 = l & 15, lq = l >> 4;
    int brow = blockIdx.x * 16;
    int kbase = blockIdx.y * 512;
    int n0 = w * 32;

    f32x4 acc[2] = { (f32x4){0.f,0.f,0.f,0.f}, (f32x4){0.f,0.f,0.f,0.f} };

    int srow = tid >> 4, sc = (tid & 15) * 16;
#pragma unroll
    for (int k0 = 0; k0 < 512; k0 += 256) {
        __syncthreads();
        const _Float16* src = h2f + (long)(brow + srow) * 4096 + kbase + k0 + sc;
        half8 v0 = *(const half8*)src;
        half8 v1 = *(const half8*)(src + 8);
        *(half8*)(&As[srow][sc])     = v0;
        *(half8*)(&As[srow][sc + 8]) = v1;
        __syncthreads();
#pragma unroll
        for (int kk = 0; kk < 256; kk += 32) {
            half8 af = *(const half8*)(&As[l15][kk + lq * 8]);
#pragma unroll
            for (int nf = 0; nf < 2; ++nf) {
                half8 bf = *(const half8*)(Wt2 + (long)(n0 + nf * 16 + l15) * 4096
                                           + kbase + k0 + kk + lq * 8);
                acc[nf] = __builtin_amdgcn_mfma_f32_16x16x32_f16(af, bf, acc[nf], 0, 0, 0);
            }
        }
    }

    float* pbase = pws + (long)blockIdx.y * 262144;
#pragma unroll
    for (int nf = 0; nf < 2; ++nf) {
        int n = n0 + nf * 16 + l15;
#pragma unroll
        for (int reg = 0; reg < 4; ++reg) {
            int b = brow + lq * 4 + reg;
            pbase[(long)b * 128 + n] = acc[nf][reg];
        }
    }
}

// ---------------------------------------------------------------------------
// Kernel 3b: fused split-K reduce + bias + relu -> featsH, then router MLP
// + 16-lane-shuffle softmax -> probs. One block per 16 batch rows.
// ---------------------------------------------------------------------------
__global__ __launch_bounds__(256) void k_reduce_router(
    const float* __restrict__ pws, const float* __restrict__ db,
    const float* __restrict__ rW1, const float* __restrict__ rb1,
    const float* __restrict__ rW2, const float* __restrict__ rb2,
    _Float16* __restrict__ featsH, float* __restrict__ probs)
{
    __shared__ float fsm[16][128];
    __shared__ float r1s[16][64];
    int tid = threadIdx.x;
    int brow = blockIdx.x * 16;
    int r = tid >> 4, c0 = (tid & 15) * 8;

    float acc[8];
#pragma unroll
    for (int j = 0; j < 8; ++j) acc[j] = db[c0 + j];
    long base = (long)(brow + r) * 128 + c0;
#pragma unroll
    for (int kc = 0; kc < 8; ++kc) {
        const float4* p = (const float4*)(pws + (long)kc * 262144 + base);
        float4 v0 = p[0], v1 = p[1];
        acc[0] += v0.x; acc[1] += v0.y; acc[2] += v0.z; acc[3] += v0.w;
        acc[4] += v1.x; acc[5] += v1.y; acc[6] += v1.z; acc[7] += v1.w;
    }
    half8 hv;
#pragma unroll
    for (int j = 0; j < 8; ++j) {
        float val = fmaxf(acc[j], 0.f);
        fsm[r][c0 + j] = val;
        hv[j] = (_Float16)val;
    }
    *(half8*)(featsH + base) = hv;
    __syncthreads();

    {
        int h = tid & 63, bg = tid >> 6;
        float a[4];
#pragma unroll
        for (int i = 0; i < 4; ++i) a[i] = rb1[h];
        for (int d = 0; d < 128; ++d) {
            float wgt = rW1[d * 64 + h];
#pragma unroll
            for (int i = 0; i < 4; ++i) a[i] += fsm[bg * 4 + i][d] * wgt;
        }
#pragma unroll
        for (int i = 0; i < 4; ++i) r1s[bg * 4 + i][h] = fmaxf(a[i], 0.f);
    }
    __syncthreads();

    {
        int b = tid >> 4, e = tid & 15;
        float a = rb2[e];
#pragma unroll 8
        for (int k = 0; k < 64; ++k) a += r1s[b][k] * rW2[k * 16 + e];
        float mx = a;
#pragma unroll
        for (int off = 1; off < 16; off <<= 1)
            mx = fmaxf(mx, __shfl_xor(mx, off, 16));
        float ex = __expf(a - mx);
        float s = ex;
#pragma unroll
        for (int off = 1; off < 16; off <<= 1)
            s += __shfl_xor(s, off, 16);
        probs[(long)(brow + b) * 16 + e] = ex / s;
    }
}

// ---------------------------------------------------------------------------
// Kernel 5: fused expert chain, f16 MFMA.
// Grid (16 experts, 32 b-tiles of 64). 4 waves x 16 rows each.
// ---------------------------------------------------------------------------
__global__ __launch_bounds__(256) void k_expert_mfma(
    const _Float16* __restrict__ featsH,
    const _Float16* __restrict__ eW1t, const float* __restrict__ eb1,
    const float* __restrict__ g,  const float* __restrict__ bb,
    const float* __restrict__ m,  const float* __restrict__ v,
    const _Float16* __restrict__ eW2t, const float* __restrict__ eb2,
    const _Float16* __restrict__ eW3p, const float* __restrict__ eb3,
    float* __restrict__ e3p)
{
    __shared__ __align__(16) _Float16 fsH[64][136];
    __shared__ __align__(16) _Float16 h1sH[64][136];
    __shared__ __align__(16) _Float16 h2sH[64][72];
    int e = blockIdx.x, bt = blockIdx.y;
    int tid = threadIdx.x;
    int w = tid >> 6, l = tid & 63, l15 = l & 15, lq = l >> 4;
    int brow = bt * 64, m0 = w * 16;

#pragma unroll
    for (int it = 0; it < 4; ++it) {
        int idx = it * 256 + tid;
        int r = idx >> 4, c = (idx & 15) * 8;
        *(half8*)&fsH[r][c] = *(const half8*)(featsH + (long)(brow + r) * 128 + c);
    }
    __syncthreads();

    // phase 1: [64x128] @ [128x128] + BN + relu
    {
        half8 af[4];
#pragma unroll
        for (int kq = 0; kq < 4; ++kq)
            af[kq] = *(const half8*)&fsH[m0 + l15][kq * 32 + lq * 8];
        const _Float16* B1 = eW1t + (long)e * 16384 + l15 * 128 + lq * 8;
        f32x4 acc[8];
#pragma unroll
        for (int nf = 0; nf < 8; ++nf) {
            float bv = eb1[e * 128 + nf * 16 + l15];
            acc[nf] = (f32x4){ bv, bv, bv, bv };
        }
#pragma unroll
        for (int nf = 0; nf < 8; ++nf)
#pragma unroll
            for (int kq = 0; kq < 4; ++kq) {
                half8 bfv = *(const half8*)(B1 + nf * 2048 + kq * 32);
                acc[nf] = __builtin_amdgcn_mfma_f32_16x16x32_f16(af[kq], bfv, acc[nf], 0, 0, 0);
            }
#pragma unroll
        for (int nf = 0; nf < 8; ++nf) {
            int h = nf * 16 + l15;
            float gg = g[e * 128 + h], bbv = bb[e * 128 + h], mm = m[e * 128 + h];
            float iv = rsqrtf(v[e * 128 + h] + EPS);
#pragma unroll
            for (int reg = 0; reg < 4; ++reg) {
                float val = fmaxf(acc[nf][reg], 0.f);
                h1sH[m0 + lq * 4 + reg][h] = (_Float16)((val - mm) * iv * gg + bbv);
            }
        }
    }
    __syncthreads();

    // phase 2: [64x128] @ [128x64] + relu
    {
        half8 af[4];
#pragma unroll
        for (int kq = 0; kq < 4; ++kq)
            af[kq] = *(const half8*)&h1sH[m0 + l15][kq * 32 + lq * 8];
        const _Float16* B2 = eW2t + (long)e * 8192 + l15 * 128 + lq * 8;
        f32x4 acc[4];
#pragma unroll
        for (int nf = 0; nf < 4; ++nf) {
            float bv = eb2[e * 64 + nf * 16 + l15];
            acc[nf] = (f32x4){ bv, bv, bv, bv };
        }
#pragma unroll
        for (int nf = 0; nf < 4; ++nf)
#pragma unroll
            for (int kq = 0; kq < 4; ++kq) {
                half8 bfv = *(const half8*)(B2 + nf * 2048 + kq * 32);
                acc[nf] = __builtin_amdgcn_mfma_f32_16x16x32_f16(af[kq], bfv, acc[nf], 0, 0, 0);
            }
#pragma unroll
        for (int nf = 0; nf < 4; ++nf)
#pragma unroll
            for (int reg = 0; reg < 4; ++reg)
                h2sH[m0 + lq * 4 + reg][nf * 16 + l15] = (_Float16)fmaxf(acc[nf][reg], 0.f);
    }
    __syncthreads();

    // phase 3: [64x64] @ [64x16(pad)] -> e3p
    {
        half8 af[2];
#pragma unroll
        for (int kq = 0; kq < 2; ++kq)
            af[kq] = *(const half8*)&h2sH[m0 + l15][kq * 32 + lq * 8];
        const _Float16* B3 = eW3p + (long)e * 1024 + l15 * 64 + lq * 8;
        float bv = (l15 < 10) ? eb3[e * 10 + l15] : 0.f;
        f32x4 acc = (f32x4){ bv, bv, bv, bv };
#pragma unroll
        for (int kq = 0; kq < 2; ++kq) {
            half8 bfv = *(const half8*)(B3 + kq * 32);
            acc = __builtin_amdgcn_mfma_f32_16x16x32_f16(af[kq], bfv, acc, 0, 0, 0);
        }
#pragma unroll
        for (int reg = 0; reg < 4; ++reg) {
            int b = brow + m0 + lq * 4 + reg;
            e3p[((long)e * 2048 + b) * 16 + l15] = acc[reg];
        }
    }
}

// ---------------------------------------------------------------------------
// Kernel 6: combine.  out[b][c] = sum_e probs[b][e] * e3p[e][b][c]
// ---------------------------------------------------------------------------
__global__ __launch_bounds__(256) void k_combine(
    const float* __restrict__ e3p, const float* __restrict__ probs,
    float* __restrict__ out)
{
    int t = blockIdx.x * blockDim.x + threadIdx.x;
    if (t >= 2048 * 10) return;
    int b = t / 10, c = t % 10;
    float acc = 0.f;
#pragma unroll
    for (int e = 0; e < 16; ++e)
        acc += probs[(long)b * 16 + e] * e3p[((long)e * 2048 + b) * 16 + c];
    out[t] = acc;
}

// ---------------------------------------------------------------------------
extern "C" void kernel_launch(void* const* d_in, const int* in_sizes, int n_in,
                              void* d_out, int out_size, void* d_ws, size_t ws_size,
                              hipStream_t stream)
{
    const float* x    = (const float*)d_in[0];
    const float* cW1  = (const float*)d_in[1];
    const float* cb1  = (const float*)d_in[2];
    const float* bn1g = (const float*)d_in[3];
    const float* bn1b = (const float*)d_in[4];
    const float* bn1m = (const float*)d_in[5];
    const float* bn1v = (const float*)d_in[6];
    const float* cW2  = (const float*)d_in[7];
    const float* cb2  = (const float*)d_in[8];
    const float* bn2g = (const float*)d_in[9];
    const float* bn2b = (const float*)d_in[10];
    const float* bn2m = (const float*)d_in[11];
    const float* bn2v = (const float*)d_in[12];
    const float* dW   = (const float*)d_in[13];
    const float* db   = (const float*)d_in[14];
    const float* rW1  = (const float*)d_in[15];
    const float* rb1  = (const float*)d_in[16];
    const float* rW2  = (const float*)d_in[17];
    const float* rb2  = (const float*)d_in[18];
    const float* eW1  = (const float*)d_in[19];
    const float* eb1  = (const float*)d_in[20];
    const float* ebng = (const float*)d_in[21];
    const float* ebnb = (const float*)d_in[22];
    const float* ebnm = (const float*)d_in[23];
    const float* ebnv = (const float*)d_in[24];
    const float* eW2  = (const float*)d_in[25];
    const float* eb2  = (const float*)d_in[26];
    const float* eW3  = (const float*)d_in[27];
    const float* eb3  = (const float*)d_in[28];

    float* ws    = (float*)d_ws;
    // --- region 1 (recycled): e3p + featsH ---
    float* h1reg = ws;
    float* e3p   = h1reg;                                  // [0 .. 524,288) floats
    _Float16* featsH = (_Float16*)(h1reg + 524288);        // 262,144 f16
    // --- region 2: h2reg ---
    float* h2reg = h1reg + 16777216;
    _Float16* h2f = (_Float16*)h2reg;                      // conv2 out f16 [2048][4096]
    _Float16* Wt2 = (_Float16*)(h2reg + 4194304);          // dense weights f16 [128][4096]
    // --- region 3: small tensors ---
    float* probs = h2reg + 8388608;        //     32,768 floats
    float* ewreg = probs + 32768;
    _Float16* eW1t = (_Float16*)ewreg;             // 262,144 f16
    _Float16* eW2t = eW1t + 262144;                // 131,072 f16
    _Float16* eW3p = eW2t + 131072;                //  16,384 f16
    _Float16* Wt   = eW3p + 16384;                 //  18,432 f16 (conv2 w)
    _Float16* Wt1  = Wt + 18432;                   //   3,072 f16 (conv1 w)
    // --- region 4: dense split-K partials [8][2048][128] fp32 ---
    float* pws   = ewreg + 262144;
    float* out   = (float*)d_out;

    k_wprep_all<<<244, 256, 0, stream>>>(dW, Wt2, eW1, eW1t, eW2, eW2t,
                                         cW1, Wt1, cW2, Wt, eW3, eW3p);
    k_conv12<<<2048, 256, 0, stream>>>(x, Wt1, cb1, bn1g, bn1b, bn1m, bn1v,
                                       Wt, cb2, bn2g, bn2b, bn2m, bn2v, h2f);
    {
        dim3 grid(128, 8);
        k_dense_mfma<<<grid, 256, 0, stream>>>(h2f, Wt2, pws);
    }
    k_reduce_router<<<128, 256, 0, stream>>>(pws, db, rW1, rb1, rW2, rb2,
                                             featsH, probs);
    {
        dim3 grid(16, 32);
        k_expert_mfma<<<grid, 256, 0, stream>>>(featsH, eW1t, eb1, ebng, ebnb, ebnm, ebnv,
                                                eW2t, eb2, eW3p, eb3, e3p);
    }
    k_combine<<<80, 256, 0, stream>>>(e3p, probs, out);
}